// Round 8
// baseline (196.653 us; speedup 1.0000x reference)
//
#include <hip/hip_runtime.h>
#include <stdint.h>

// ---------------------------------------------------------------------------
// Problem constants
// ---------------------------------------------------------------------------
#define NSEQ 512        // B*N
#define HIDN 128

// ws byte offsets
#define OFF_BIAS_E 0                            // 512 f32
#define OFF_BIAS_D 2048                         // 512 f32
#define OFF_W1P    4096                         // conv w1 f16 pairs [288][64]
#define OFF_W2P    77824                        // conv w2 f16 pairs [32][64]
#define OFF_FLAT   86016                        // [16384] int
#define OFF_W1H    151552                       // head W1 f16 pairs [64][64]
#define OFF_FEIH   167936                       // enc Wih frags (32gt x 2kt), 64 KB
#define OFF_FEHH   233472                       // enc Whh frags (32gt x 4kt), 128 KB
#define OFF_FDIH   364544                       // dec Wih frags, 128 KB
#define OFF_FDHH   495616                       // dec Whh frags, 128 KB
#define OFF_DOTS   (1024*1024)                  // [32][512][64] f16 = 2 MB
#define OFF_DG_FB  (3*1024*1024)                // fallback dec-h area
#define OFF_XT     (4*1024*1024)                // xT [16][128][128][64] f16 = 33.5 MB
#define WS_NEED_XT ((size_t)(4*1024*1024) + (size_t)16*128*128*64*2 + 1024)

typedef _Float16 h2f __attribute__((ext_vector_type(2)));
typedef _Float16 f16x8 __attribute__((ext_vector_type(8)));
typedef float    f32x4 __attribute__((ext_vector_type(4)));

static __device__ __forceinline__ h2f u2h(uint32_t u) {
  union { uint32_t u; h2f h; } v; v.u = u; return v.h;
}

#if __has_builtin(__builtin_amdgcn_fdot2)
static __device__ __forceinline__ float fdot2_(uint32_t a, uint32_t b, float c) {
  return __builtin_amdgcn_fdot2(u2h(a), u2h(b), c, false);
}
#else
static __device__ __forceinline__ float fdot2_(uint32_t a, uint32_t b, float c) {
  h2f x = u2h(a), y = u2h(b);
  return c + (float)x.x * (float)y.x + (float)x.y * (float)y.y;
}
#endif

static __device__ __forceinline__ uint32_t packh(float a, float b) {
  union { _Float16 h[2]; uint32_t u; } v;
  v.h[0] = (_Float16)a; v.h[1] = (_Float16)b; return v.u;
}
static __device__ __forceinline__ float sig_(float x) {
  return 1.0f / (1.0f + __expf(-x));
}
static __device__ __forceinline__ float tanh_(float x) {
  return 1.0f - 2.0f / (1.0f + __expf(2.0f * x));
}

// Volatile-asm fragment load: value is asm-produced -> compiler CANNOT
// rematerialize it; with budget >= live set it must stay in registers.
static __device__ __forceinline__ f16x8 ldg_frag(const f16x8* p) {
  f16x8 r;
  asm volatile("global_load_dwordx4 %0, %1, off" : "=v"(r) : "v"(p));
  return r;
}
static __device__ __forceinline__ void frag_fence() {
  asm volatile("s_waitcnt vmcnt(0)" ::: "memory");
  __builtin_amdgcn_sched_barrier(0);
}

// ---------------------------------------------------------------------------
// Kernel 0: weight prep.
// MFMA A-frag, 16x16x32_f16: lane l, j in 0..7: A[row=l&15][k=(l>>4)*8+j].
// GATE PERMUTATION: tile gt, row16 -> W row g = (row16&3)*128 + gt*4 + (row16>>2)
// k map (must match B build): k = kt*32 + (l>>4)*8 + 2*j2 (+0,+1).
// ---------------------------------------------------------------------------
__global__ __launch_bounds__(256) void prep_kernel(
    const float* Wih_e, const float* Whh_e,
    const float* bih_e, const float* bhh_e,
    const float* Wih_d, const float* Whh_d,
    const float* bih_d, const float* bhh_d,
    const float* w1, const float* w2, const float* W1, char* ws, int w1_order) {
  float*    bias_e = (float*)(ws + OFF_BIAS_E);
  float*    bias_d = (float*)(ws + OFF_BIAS_D);
  uint32_t* w1p    = (uint32_t*)(ws + OFF_W1P);
  uint32_t* w2p    = (uint32_t*)(ws + OFF_W2P);
  uint32_t* W1h    = (uint32_t*)(ws + OFF_W1H);

  int idx = blockIdx.x * 256 + threadIdx.x;
  if (idx < 512) { bias_e[idx] = bih_e[idx] + bhh_e[idx]; return; }
  idx -= 512;
  if (idx < 512) { bias_d[idx] = bih_d[idx] + bhh_d[idx]; return; }
  idx -= 512;
  if (idx < 288*64) {                             // conv w1 pairs [i2][c]
    int i2 = idx >> 6, c = idx & 63;
    if (w1_order) {
      int tap = i2 >> 5, cin = (i2 & 31) * 2;     // i2 = tap*32 + c2
      w1p[idx] = packh(w1[c*576 + cin*9 + tap], w1[c*576 + (cin+1)*9 + tap]);
    } else {
      w1p[idx] = packh(w1[c*576 + 2*i2], w1[c*576 + 2*i2 + 1]);
    }
    return;
  }
  idx -= 288*64;
  if (idx < 32*64) {                              // conv w2 pairs [c2][d]
    int c2 = idx >> 6, d = idx & 63;
    w2p[idx] = packh(w2[d*64 + 2*c2], w2[d*64 + 2*c2 + 1]);
    return;
  }
  idx -= 32*64;
  if (idx < 64*64) {                              // head W1 pairs [k2][j]
    int k2 = idx >> 6, j = idx & 63;
    W1h[idx] = packh(W1[j*128 + 2*k2], W1[j*128 + 2*k2 + 1]);
    return;
  }
  idx -= 64*64;
  if (idx < 16384) {                              // feih: 32gt x 2kt, k<64
    int j2 = idx & 3, lane = (idx >> 2) & 63, kt = (idx >> 8) & 1, gt = idx >> 9;
    int row16 = lane & 15;
    int g = (row16 & 3)*128 + gt*4 + (row16 >> 2);
    int k = kt*32 + (lane >> 4)*8 + 2*j2;
    ((uint32_t*)(ws + OFF_FEIH))[idx] = packh(Wih_e[g*64 + k], Wih_e[g*64 + k + 1]);
    return;
  }
  idx -= 16384;
  if (idx < 3*32768) {                            // fehh / fdih / fdhh: 32gt x 4kt
    int which = idx >> 15, r = idx & 32767;
    int j2 = r & 3, lane = (r >> 2) & 63, kt = (r >> 8) & 3, gt = r >> 10;
    int row16 = lane & 15;
    int g = (row16 & 3)*128 + gt*4 + (row16 >> 2);
    int k = kt*32 + (lane >> 4)*8 + 2*j2;
    const float* W = (which == 0) ? Whh_e : ((which == 1) ? Wih_d : Whh_d);
    uint32_t* dst = (uint32_t*)(ws + ((which == 0) ? OFF_FEHH :
                                      (which == 1) ? OFF_FDIH : OFF_FDHH));
    dst[r] = packh(W[g*128 + k], W[g*128 + k + 1]);
    return;
  }
}
#define PREP_TOTAL (512 + 512 + 288*64 + 32*64 + 64*64 + 16384 + 3*32768)

// ---------------------------------------------------------------------------
// Kernel 1: point math -> gt (output 1) + flat indices
// ---------------------------------------------------------------------------
__global__ __launch_bounds__(256) void points_kernel(
    const float* mask_point, float* out_gt, int* flat) {
  int p = blockIdx.x * 256 + threadIdx.x;
  if (p >= 16384) return;
  float mx = mask_point[p*2 + 0];
  float my = mask_point[p*2 + 1];
  float fx = fminf(mx * 0.25f, 127.0f);
  float fy = fminf(my * 0.25f, 127.0f);
  out_gt[p*2 + 0] = fx * 4.0f;
  out_gt[p*2 + 1] = fy * 4.0f;
  flat[p] = (int)(__fmaf_rn(fy, 128.0f, fx));   // fy*128 exact -> fma == mul+add
}

// ---------------------------------------------------------------------------
// Kernel T: x [16][64][128][128] f32 -> xT [16][128][128][64] f16 (NHWC)
// ---------------------------------------------------------------------------
__global__ __launch_bounds__(256, 2) void transpose_kernel(
    const float* x, uint32_t* xT32) {
  __shared__ float lds[64][257];
  int bid = blockIdx.x;           // 1024 = 16 b x 16 yt x 4 xt
  int xt = bid & 3, yt = (bid >> 2) & 15, b = bid >> 6;
  int x0 = xt * 32, y0 = yt * 8;
  int tx = threadIdx.x & 31, ty = threadIdx.x >> 5;
  #pragma unroll 8
  for (int c = 0; c < 64; ++c)
    lds[c][ty*32 + tx] = x[((b*64 + c)*128 + (y0 + ty))*128 + (x0 + tx)];
  __syncthreads();
  #pragma unroll 8
  for (int r = 0; r < 32; ++r) {
    int i = threadIdx.x + 256*r;    // i = pos*32 + c2
    int c2 = i & 31, pos = i >> 5;
    int yy = pos >> 5, xx = pos & 31;
    float lo = lds[2*c2][yy*32 + xx], hi = lds[2*c2 + 1][yy*32 + xx];
    xT32[((b*128 + y0 + yy)*128 + (x0 + xx))*32 + c2] = packh(lo, hi);
  }
}

// ---------------------------------------------------------------------------
// Kernel 2: fused gathered conv (3x3 -> ReLU -> 1x1) at points, 4 pts/group
// ---------------------------------------------------------------------------
template <int MODE>
__global__ __launch_bounds__(256, 2) void conv_gather_kernel(
    const float* x, const uint32_t* xT32, const int* point_mask,
    const float* conv1_b, const float* conv2_b,
    const char* ws_ro, _Float16* dots_h, const int* flat) {
  __shared__ uint32_t w1s[64*292];    // 74752 B (292: 16B-aligned rows)
  __shared__ uint32_t patch2[4*288];  //  4608 B
  __shared__ uint32_t tl2[4*32];      //   512 B

  const uint32_t* w1p = (const uint32_t*)(ws_ro + OFF_W1P);
  const uint32_t* w2p = (const uint32_t*)(ws_ro + OFF_W2P);
  int tid = threadIdx.x;
  for (int i = tid; i < 288*64; i += 256) {
    int i2 = i >> 6, cc = i & 63;
    w1s[cc*292 + i2] = w1p[i];
  }

  int q = tid >> 6, c = tid & 63;
  float c1b = conv1_b[c], c2b = conv2_b[c];

  for (int g = 0; g < 8; ++g) {
    int p0 = blockIdx.x * 32 + g * 4;
    __syncthreads();
    if (MODE == 1) {
      #pragma unroll
      for (int r = 0; r < 5; ++r) {  // 1152 u32 = 4 pts x 288
        int u = tid + 256*r;
        if (u < 1152) {
          int slot = u / 288, w = u - slot*288;
          int tap = w >> 5, c2i = w & 31;
          int p = p0 + slot;
          int fl = flat[p];
          int hh = fl >> 7, ww = fl & 127;
          int b = p >> 10;
          int dy = tap / 3, dx = tap - dy*3;
          int yy = hh + dy - 1, xx = ww + dx - 1;
          uint32_t v = 0u;
          if (yy >= 0 && yy < 128 && xx >= 0 && xx < 128)
            v = xT32[((b*128 + yy)*128 + xx)*32 + c2i];
          patch2[slot*288 + w] = v;
        }
      }
    } else {
      #pragma unroll
      for (int r = 0; r < 9; ++r) {  // 2304 halves = 4 pts x 576
        int l = tid + 256*r;
        int slot = l / 576;
        int within = l - slot*576;
        int cp = within / 9;
        int tap = within - cp*9;
        int p = p0 + slot;
        int fl = flat[p];
        int hh = fl >> 7, ww = fl & 127;
        int b = p >> 10;
        int yy = hh + tap/3 - 1, xx = ww + tap%3 - 1;
        float v = 0.0f;
        if (yy >= 0 && yy < 128 && xx >= 0 && xx < 128)
          v = x[((b*64 + cp)*128 + yy)*128 + xx];
        ((_Float16*)patch2)[l] = (_Float16)v;
      }
    }
    __syncthreads();

    float a0 = c1b, a1 = 0.f, a2 = 0.f, a3 = 0.f;
    int cbase = c * 292, pbase = q * 288;
    #pragma unroll 4
    for (int i2 = 0; i2 < 288; i2 += 4) {
      a0 = fdot2_(w1s[cbase + i2+0], patch2[pbase + i2+0], a0);
      a1 = fdot2_(w1s[cbase + i2+1], patch2[pbase + i2+1], a1);
      a2 = fdot2_(w1s[cbase + i2+2], patch2[pbase + i2+2], a2);
      a3 = fdot2_(w1s[cbase + i2+3], patch2[pbase + i2+3], a3);
    }
    float t1 = fmaxf((a0 + a1) + (a2 + a3), 0.0f);
    ((_Float16*)tl2)[q*64 + c] = (_Float16)t1;
    // tl2[q] written/read by same wave -> no barrier

    float acc2 = c2b;
    #pragma unroll
    for (int c2i = 0; c2i < 32; ++c2i)
      acc2 = fdot2_(w2p[c2i*64 + c], tl2[q*32 + c2i], acc2);
    int p = p0 + q;
    acc2 *= (float)point_mask[p];
    int k = p & 31, bn = p >> 5;
    dots_h[(k*NSEQ + bn)*64 + c] = (_Float16)acc2;   // time-major [k][bn][d]
  }
}

// ---------------------------------------------------------------------------
// Kernel 3: recurrent LSTMs via gate-permuted MFMA, 16 seqs/block.
// 32 blocks x 512 threads (8 waves). Wave w owns gt = 4w .. 4w+3.
// Weight fragments loaded by VOLATILE ASM (non-rematerializable) -> resident.
// B cols 0..15 = the block's 16 sequences. 1 barrier/step (dbuf h).
// ebuf overlay: row t holds x[t] during encoder, then enc h[t].
// ---------------------------------------------------------------------------
__global__ __launch_bounds__(512)
__attribute__((amdgpu_waves_per_eu(2, 4)))
void lstm_kernel(const char* ws_ro, _Float16* dg) {
  const f16x8* feih   = (const f16x8*)(ws_ro + OFF_FEIH);
  const f16x8* fehh   = (const f16x8*)(ws_ro + OFF_FEHH);
  const f16x8* fdih   = (const f16x8*)(ws_ro + OFF_FDIH);
  const f16x8* fdhh   = (const f16x8*)(ws_ro + OFF_FDHH);
  const float* bias_e = (const float*)(ws_ro + OFF_BIAS_E);
  const float* bias_d = (const float*)(ws_ro + OFF_BIAS_D);
  const uint32_t* dots_u = (const uint32_t*)(ws_ro + OFF_DOTS);

  __shared__ __attribute__((aligned(16))) uint32_t ebuf[32][16][68]; // 136 KB
  __shared__ __attribute__((aligned(16))) uint32_t hb2[2][16][68];   // 8.5 KB

  int tid  = threadIdx.x;
  int lane = tid & 63, wave = tid >> 6;       // 8 waves
  int col  = lane & 15, lgrp = lane >> 4;
  int bn0  = blockIdx.x * 16;
  int gtb  = wave * 4;                        // 4 gate-tiles per wave

  // stage x: [t][col][32 u32], coalesced
  for (int i = tid; i < 16384; i += 512) {
    int t = i >> 9, rem = i & 511, c = rem >> 5, k2 = rem & 31;
    ebuf[t][c][k2] = dots_u[(t*NSEQ + bn0 + c)*32 + k2];
  }
  for (int i = tid; i < 2*16*68; i += 512) ((uint32_t*)hb2)[i] = 0u;

  // ---- encoder weights: 24 asm-pinned frags (96 VGPR) ----
  f16x8 fa[4][2], fb[4][4];
  float be[4][4];
  #pragma unroll
  for (int ti = 0; ti < 4; ++ti) {
    int gt = gtb + ti;
    #pragma unroll
    for (int kt = 0; kt < 2; ++kt) fa[ti][kt] = ldg_frag(&feih[(gt*2 + kt)*64 + lane]);
    #pragma unroll
    for (int kt = 0; kt < 4; ++kt) fb[ti][kt] = ldg_frag(&fehh[(gt*4 + kt)*64 + lane]);
    #pragma unroll
    for (int r = 0; r < 4; ++r) be[ti][r] = bias_e[r*128 + gt*4 + lgrp];
  }
  frag_fence();

  float cst[4] = {0.f, 0.f, 0.f, 0.f};
  _Float16 hvp[4] = {(_Float16)0.f, (_Float16)0.f, (_Float16)0.f, (_Float16)0.f};
  int par = 0;
  __syncthreads();

  // ----------------- encoder -----------------
  for (int t = 0; t < 32; ++t) {
    f16x8 bx[2], bh[4];
    #pragma unroll
    for (int kt = 0; kt < 2; ++kt)
      bx[kt] = *(const f16x8*)&ebuf[t][col][kt*16 + lgrp*4];
    #pragma unroll
    for (int kt = 0; kt < 4; ++kt)
      bh[kt] = *(const f16x8*)&hb2[par][col][kt*16 + lgrp*4];
    #pragma unroll
    for (int ti = 0; ti < 4; ++ti) {
      f32x4 ac = {be[ti][0], be[ti][1], be[ti][2], be[ti][3]};
      #pragma unroll
      for (int kt = 0; kt < 2; ++kt)
        ac = __builtin_amdgcn_mfma_f32_16x16x32_f16(fa[ti][kt], bx[kt], ac, 0, 0, 0);
      #pragma unroll
      for (int kt = 0; kt < 4; ++kt)
        ac = __builtin_amdgcn_mfma_f32_16x16x32_f16(fb[ti][kt], bh[kt], ac, 0, 0, 0);
      float ig = sig_(ac[0]), fg = sig_(ac[1]);
      float gg = tanh_(ac[2]), og = sig_(ac[3]);
      cst[ti] = fg * cst[ti] + ig * gg;
      float hh = og * tanh_(cst[ti]);
      int u = (gtb + ti)*4 + lgrp;
      _Float16 hv = (_Float16)hh;
      ((_Float16*)&hb2[par^1][col][0])[u] = hv;
      if (t > 0) ((_Float16*)&ebuf[t-1][col][0])[u] = hvp[ti]; // retire h[t-1]
      hvp[ti] = hv;
    }
    __syncthreads();
    par ^= 1;
  }
  // retire h[31]
  #pragma unroll
  for (int ti = 0; ti < 4; ++ti) {
    int u = (gtb + ti)*4 + lgrp;
    ((_Float16*)&ebuf[31][col][0])[u] = hvp[ti];
  }

  // ---- decoder weights: 32 asm-pinned frags (128 VGPR) ----
  f16x8 da[4][4], db[4][4];
  float bd[4][4];
  #pragma unroll
  for (int ti = 0; ti < 4; ++ti) {
    int gt = gtb + ti;
    #pragma unroll
    for (int kt = 0; kt < 4; ++kt) {
      da[ti][kt] = ldg_frag(&fdih[(gt*4 + kt)*64 + lane]);
      db[ti][kt] = ldg_frag(&fdhh[(gt*4 + kt)*64 + lane]);
    }
    #pragma unroll
    for (int r = 0; r < 4; ++r) bd[ti][r] = bias_d[r*128 + gt*4 + lgrp];
  }
  frag_fence();
  __syncthreads();

  // ----------------- decoder -----------------
  for (int t = 0; t < 32; ++t) {
    f16x8 bx[4], bh[4];
    #pragma unroll
    for (int kt = 0; kt < 4; ++kt) {
      bx[kt] = *(const f16x8*)&ebuf[t][col][kt*16 + lgrp*4];
      bh[kt] = *(const f16x8*)&hb2[par][col][kt*16 + lgrp*4];
    }
    #pragma unroll
    for (int ti = 0; ti < 4; ++ti) {
      f32x4 ac = {bd[ti][0], bd[ti][1], bd[ti][2], bd[ti][3]};
      #pragma unroll
      for (int kt = 0; kt < 4; ++kt)
        ac = __builtin_amdgcn_mfma_f32_16x16x32_f16(da[ti][kt], bx[kt], ac, 0, 0, 0);
      #pragma unroll
      for (int kt = 0; kt < 4; ++kt)
        ac = __builtin_amdgcn_mfma_f32_16x16x32_f16(db[ti][kt], bh[kt], ac, 0, 0, 0);
      float ig = sig_(ac[0]), fg = sig_(ac[1]);
      float gg = tanh_(ac[2]), og = sig_(ac[3]);
      cst[ti] = fg * cst[ti] + ig * gg;
      float hh = og * tanh_(cst[ti]);
      int u = (gtb + ti)*4 + lgrp;
      _Float16 hv = (_Float16)hh;
      ((_Float16*)&hb2[par^1][col][0])[u] = hv;
      dg[(size_t)((bn0 + col)*32 + t)*128 + u] = hv;      // for head kernel
    }
    __syncthreads();
    par ^= 1;
  }
}

// ---------------------------------------------------------------------------
// Kernel 4: MLP head over all 16384 rows: y = relu(h@W1.T+b1)@W2.T+b2
// 256 blocks x 512 threads; 64 rows/block.
// ---------------------------------------------------------------------------
__global__ __launch_bounds__(512, 2) void head_kernel(
    const char* ws_ro, const _Float16* dg, const float* b1,
    const float* W2, const float* b2, float* out_kp) {
  const uint32_t* W1h = (const uint32_t*)(ws_ro + OFF_W1H);
  __shared__ uint32_t hs[64][68];   // 17.4 KB
  __shared__ float hidf[64][65];    // 16.6 KB
  int tid = threadIdx.x;
  int r0 = blockIdx.x * 64;
  const uint32_t* dgu = (const uint32_t*)dg;
  for (int i = tid; i < 64*64; i += 512) {
    int r = i >> 6, k = i & 63;
    hs[r][k] = dgu[(size_t)(r0 + r)*64 + k];
  }
  __syncthreads();
  int j = tid & 63, w = tid >> 6;   // 8 waves; rows w + 8m
  float acc[8];
  #pragma unroll
  for (int m = 0; m < 8; ++m) acc[m] = b1[j];
  #pragma unroll 8
  for (int k = 0; k < 64; ++k) {
    uint32_t wv = W1h[k*64 + j];
    #pragma unroll
    for (int m = 0; m < 8; ++m)
      acc[m] = fdot2_(wv, hs[w + 8*m][k], acc[m]);
  }
  #pragma unroll
  for (int m = 0; m < 8; ++m)
    hidf[w + 8*m][j] = fmaxf(acc[m], 0.0f);
  __syncthreads();
  if (tid < 128) {
    int r = tid >> 1, e = tid & 1;
    float a = b2[e];
    #pragma unroll 16
    for (int jj = 0; jj < 64; ++jj) a += W2[e*64 + jj] * hidf[r][jj];
    out_kp[(r0 + r)*2 + e] = a;
  }
}

// ---------------------------------------------------------------------------
// Launch
// ---------------------------------------------------------------------------
extern "C" void kernel_launch(void* const* d_in, const int* in_sizes, int n_in,
                              void* d_out, int out_size, void* d_ws, size_t ws_size,
                              hipStream_t stream) {
  const float* x          = (const float*)d_in[0];
  const float* mask_point = (const float*)d_in[1];
  const int*   point_mask = (const int*)d_in[2];
  const float* conv1_w    = (const float*)d_in[3];
  const float* conv1_b    = (const float*)d_in[4];
  const float* conv2_w    = (const float*)d_in[5];
  const float* conv2_b    = (const float*)d_in[6];
  const float* Wih_e      = (const float*)d_in[7];
  const float* Whh_e      = (const float*)d_in[8];
  const float* bih_e      = (const float*)d_in[9];
  const float* bhh_e      = (const float*)d_in[10];
  const float* Wih_d      = (const float*)d_in[11];
  const float* Whh_d      = (const float*)d_in[12];
  const float* bih_d      = (const float*)d_in[13];
  const float* bhh_d      = (const float*)d_in[14];
  const float* W1         = (const float*)d_in[15];
  const float* b1         = (const float*)d_in[16];
  const float* W2         = (const float*)d_in[17];
  const float* b2         = (const float*)d_in[18];

  float* out = (float*)d_out;
  char*  ws  = (char*)d_ws;

  const bool use_xt = (ws_size >= WS_NEED_XT);
  // dec-h buffer overlays the xT region (dead after conv_gather)
  _Float16* dg = (_Float16*)(ws + (use_xt ? OFF_XT : OFF_DG_FB));

  prep_kernel<<<(PREP_TOTAL + 255)/256, 256, 0, stream>>>(
      Wih_e, Whh_e, bih_e, bhh_e, Wih_d, Whh_d, bih_d, bhh_d,
      conv1_w, conv2_w, W1, ws, use_xt ? 1 : 0);

  points_kernel<<<64, 256, 0, stream>>>(
      mask_point, out + 32768, (int*)(ws + OFF_FLAT));

  if (use_xt) {
    transpose_kernel<<<1024, 256, 0, stream>>>(x, (uint32_t*)(ws + OFF_XT));
    conv_gather_kernel<1><<<512, 256, 0, stream>>>(
        x, (const uint32_t*)(ws + OFF_XT), point_mask, conv1_b, conv2_b,
        ws, (_Float16*)(ws + OFF_DOTS), (const int*)(ws + OFF_FLAT));
  } else {
    conv_gather_kernel<0><<<512, 256, 0, stream>>>(
        x, nullptr, point_mask, conv1_b, conv2_b,
        ws, (_Float16*)(ws + OFF_DOTS), (const int*)(ws + OFF_FLAT));
  }

  lstm_kernel<<<32, 512, 0, stream>>>(ws, dg);

  head_kernel<<<256, 512, 0, stream>>>(ws, dg, b1, W2, b2, out);
}

// Round 9
// 193.884 us; speedup vs baseline: 1.0143x; 1.0143x over previous
//
#include <hip/hip_runtime.h>
#include <stdint.h>

// ---------------------------------------------------------------------------
// Problem constants
// ---------------------------------------------------------------------------
#define NSEQ 512        // B*N
#define HIDN 128

// ws byte offsets
#define OFF_BIAS_E 0                            // 512 f32
#define OFF_BIAS_D 2048                         // 512 f32
#define OFF_W1P    4096                         // conv w1 f16 pairs [288][64]
#define OFF_W2P    77824                        // conv w2 f16 pairs [32][64]
#define OFF_FLAT   86016                        // [16384] int
#define OFF_W1H    151552                       // head W1 f16 pairs [64][64]
#define OFF_FEIH   167936                       // enc Wih frags (32gt x 2kt), 64 KB
#define OFF_FEHH   233472                       // enc Whh frags (32gt x 4kt), 128 KB
#define OFF_FDIH   364544                       // dec Wih frags, 128 KB
#define OFF_FDHH   495616                       // dec Whh frags, 128 KB
#define OFF_DOTS   (1024*1024)                  // [32][512][64] f16 = 2 MB
#define OFF_XT     (4*1024*1024)                // xT [16][128][128][64] f16 = 33.5 MB
#define WS_NEED_XT ((size_t)(4*1024*1024) + (size_t)16*128*128*64*2 + 1024)

typedef _Float16 h2f __attribute__((ext_vector_type(2)));
typedef _Float16 f16x8 __attribute__((ext_vector_type(8)));
typedef float    f32x4 __attribute__((ext_vector_type(4)));

static __device__ __forceinline__ h2f u2h(uint32_t u) {
  union { uint32_t u; h2f h; } v; v.u = u; return v.h;
}

#if __has_builtin(__builtin_amdgcn_fdot2)
static __device__ __forceinline__ float fdot2_(uint32_t a, uint32_t b, float c) {
  return __builtin_amdgcn_fdot2(u2h(a), u2h(b), c, false);
}
#else
static __device__ __forceinline__ float fdot2_(uint32_t a, uint32_t b, float c) {
  h2f x = u2h(a), y = u2h(b);
  return c + (float)x.x * (float)y.x + (float)x.y * (float)y.y;
}
#endif

static __device__ __forceinline__ uint32_t packh(float a, float b) {
  union { _Float16 h[2]; uint32_t u; } v;
  v.h[0] = (_Float16)a; v.h[1] = (_Float16)b; return v.u;
}
static __device__ __forceinline__ float sig_(float x) {
  return 1.0f / (1.0f + __expf(-x));
}
static __device__ __forceinline__ float tanh_(float x) {
  return 1.0f - 2.0f / (1.0f + __expf(2.0f * x));
}

// Volatile-asm fragment load: value is asm-produced -> compiler CANNOT
// rematerialize it; with budget >= live set it must stay in registers.
static __device__ __forceinline__ f16x8 ldg_frag(const f16x8* p) {
  f16x8 r;
  asm volatile("global_load_dwordx4 %0, %1, off" : "=v"(r) : "v"(p));
  return r;
}
static __device__ __forceinline__ void frag_fence() {
  asm volatile("s_waitcnt vmcnt(0)" ::: "memory");
  __builtin_amdgcn_sched_barrier(0);
}

// ---------------------------------------------------------------------------
// Kernel 0: weight prep + point math.
// MFMA A-frag, 16x16x32_f16: lane l, j in 0..7: A[row=l&15][k=(l>>4)*8+j].
// GATE PERMUTATION: tile gt, row16 -> W row g = (row16&3)*128 + gt*4 + (row16>>2)
// k map (must match B build): k = kt*32 + (l>>4)*8 + 2*j2 (+0,+1).
// ---------------------------------------------------------------------------
__global__ __launch_bounds__(256) void prep_kernel(
    const float* Wih_e, const float* Whh_e,
    const float* bih_e, const float* bhh_e,
    const float* Wih_d, const float* Whh_d,
    const float* bih_d, const float* bhh_d,
    const float* w1, const float* w2, const float* W1,
    const float* mask_point, float* out_gt, int* flat,
    char* ws, int w1_order) {
  float*    bias_e = (float*)(ws + OFF_BIAS_E);
  float*    bias_d = (float*)(ws + OFF_BIAS_D);
  uint32_t* w1p    = (uint32_t*)(ws + OFF_W1P);
  uint32_t* w2p    = (uint32_t*)(ws + OFF_W2P);
  uint32_t* W1h    = (uint32_t*)(ws + OFF_W1H);

  int idx = blockIdx.x * 256 + threadIdx.x;
  if (idx < 512) { bias_e[idx] = bih_e[idx] + bhh_e[idx]; return; }
  idx -= 512;
  if (idx < 512) { bias_d[idx] = bih_d[idx] + bhh_d[idx]; return; }
  idx -= 512;
  if (idx < 288*64) {                             // conv w1 pairs [i2][c]
    int i2 = idx >> 6, c = idx & 63;
    if (w1_order) {
      int tap = i2 >> 5, cin = (i2 & 31) * 2;     // i2 = tap*32 + c2
      w1p[idx] = packh(w1[c*576 + cin*9 + tap], w1[c*576 + (cin+1)*9 + tap]);
    } else {
      w1p[idx] = packh(w1[c*576 + 2*i2], w1[c*576 + 2*i2 + 1]);
    }
    return;
  }
  idx -= 288*64;
  if (idx < 32*64) {                              // conv w2 pairs [c2][d]
    int c2 = idx >> 6, d = idx & 63;
    w2p[idx] = packh(w2[d*64 + 2*c2], w2[d*64 + 2*c2 + 1]);
    return;
  }
  idx -= 32*64;
  if (idx < 64*64) {                              // head W1 pairs [k2][j]
    int k2 = idx >> 6, j = idx & 63;
    W1h[idx] = packh(W1[j*128 + 2*k2], W1[j*128 + 2*k2 + 1]);
    return;
  }
  idx -= 64*64;
  if (idx < 16384) {                              // feih: 32gt x 2kt, k<64
    int j2 = idx & 3, lane = (idx >> 2) & 63, kt = (idx >> 8) & 1, gt = idx >> 9;
    int row16 = lane & 15;
    int g = (row16 & 3)*128 + gt*4 + (row16 >> 2);
    int k = kt*32 + (lane >> 4)*8 + 2*j2;
    ((uint32_t*)(ws + OFF_FEIH))[idx] = packh(Wih_e[g*64 + k], Wih_e[g*64 + k + 1]);
    return;
  }
  idx -= 16384;
  if (idx < 3*32768) {                            // fehh / fdih / fdhh: 32gt x 4kt
    int which = idx >> 15, r = idx & 32767;
    int j2 = r & 3, lane = (r >> 2) & 63, kt = (r >> 8) & 3, gt = r >> 10;
    int row16 = lane & 15;
    int g = (row16 & 3)*128 + gt*4 + (row16 >> 2);
    int k = kt*32 + (lane >> 4)*8 + 2*j2;
    const float* W = (which == 0) ? Whh_e : ((which == 1) ? Wih_d : Whh_d);
    uint32_t* dst = (uint32_t*)(ws + ((which == 0) ? OFF_FEHH :
                                      (which == 1) ? OFF_FDIH : OFF_FDHH));
    dst[r] = packh(W[g*128 + k], W[g*128 + k + 1]);
    return;
  }
  idx -= 3*32768;
  if (idx < 16384) {                              // point math -> gt + flat
    float mx = mask_point[idx*2 + 0];
    float my = mask_point[idx*2 + 1];
    float fx = fminf(mx * 0.25f, 127.0f);
    float fy = fminf(my * 0.25f, 127.0f);
    out_gt[idx*2 + 0] = fx * 4.0f;
    out_gt[idx*2 + 1] = fy * 4.0f;
    flat[idx] = (int)(__fmaf_rn(fy, 128.0f, fx)); // fy*128 exact
    return;
  }
}
#define PREP_TOTAL (512 + 512 + 288*64 + 32*64 + 64*64 + 16384 + 3*32768 + 16384)

// ---------------------------------------------------------------------------
// Kernel T: x [16][64][128][128] f32 -> xT [16][128][128][64] f16 (NHWC)
// ---------------------------------------------------------------------------
__global__ __launch_bounds__(256, 2) void transpose_kernel(
    const float* x, uint32_t* xT32) {
  __shared__ float lds[64][257];
  int bid = blockIdx.x;           // 1024 = 16 b x 16 yt x 4 xt
  int xt = bid & 3, yt = (bid >> 2) & 15, b = bid >> 6;
  int x0 = xt * 32, y0 = yt * 8;
  int tx = threadIdx.x & 31, ty = threadIdx.x >> 5;
  #pragma unroll 8
  for (int c = 0; c < 64; ++c)
    lds[c][ty*32 + tx] = x[((b*64 + c)*128 + (y0 + ty))*128 + (x0 + tx)];
  __syncthreads();
  #pragma unroll 8
  for (int r = 0; r < 32; ++r) {
    int i = threadIdx.x + 256*r;    // i = pos*32 + c2
    int c2 = i & 31, pos = i >> 5;
    int yy = pos >> 5, xx = pos & 31;
    float lo = lds[2*c2][yy*32 + xx], hi = lds[2*c2 + 1][yy*32 + xx];
    xT32[((b*128 + y0 + yy)*128 + (x0 + xx))*32 + c2] = packh(lo, hi);
  }
}

// ---------------------------------------------------------------------------
// Kernel 2: fused gathered conv (3x3 -> ReLU -> 1x1) at points, 4 pts/group
// ---------------------------------------------------------------------------
template <int MODE>
__global__ __launch_bounds__(256, 2) void conv_gather_kernel(
    const float* x, const uint32_t* xT32, const int* point_mask,
    const float* conv1_b, const float* conv2_b,
    const char* ws_ro, _Float16* dots_h, const int* flat) {
  __shared__ uint32_t w1s[64*292];    // 74752 B (292: 16B-aligned rows)
  __shared__ uint32_t patch2[4*288];  //  4608 B
  __shared__ uint32_t tl2[4*32];      //   512 B

  const uint32_t* w1p = (const uint32_t*)(ws_ro + OFF_W1P);
  const uint32_t* w2p = (const uint32_t*)(ws_ro + OFF_W2P);
  int tid = threadIdx.x;
  for (int i = tid; i < 288*64; i += 256) {
    int i2 = i >> 6, cc = i & 63;
    w1s[cc*292 + i2] = w1p[i];
  }

  int q = tid >> 6, c = tid & 63;
  float c1b = conv1_b[c], c2b = conv2_b[c];

  for (int g = 0; g < 8; ++g) {
    int p0 = blockIdx.x * 32 + g * 4;
    __syncthreads();
    if (MODE == 1) {
      #pragma unroll
      for (int r = 0; r < 5; ++r) {  // 1152 u32 = 4 pts x 288
        int u = tid + 256*r;
        if (u < 1152) {
          int slot = u / 288, w = u - slot*288;
          int tap = w >> 5, c2i = w & 31;
          int p = p0 + slot;
          int fl = flat[p];
          int hh = fl >> 7, ww = fl & 127;
          int b = p >> 10;
          int dy = tap / 3, dx = tap - dy*3;
          int yy = hh + dy - 1, xx = ww + dx - 1;
          uint32_t v = 0u;
          if (yy >= 0 && yy < 128 && xx >= 0 && xx < 128)
            v = xT32[((b*128 + yy)*128 + xx)*32 + c2i];
          patch2[slot*288 + w] = v;
        }
      }
    } else {
      #pragma unroll
      for (int r = 0; r < 9; ++r) {  // 2304 halves = 4 pts x 576
        int l = tid + 256*r;
        int slot = l / 576;
        int within = l - slot*576;
        int cp = within / 9;
        int tap = within - cp*9;
        int p = p0 + slot;
        int fl = flat[p];
        int hh = fl >> 7, ww = fl & 127;
        int b = p >> 10;
        int yy = hh + tap/3 - 1, xx = ww + tap%3 - 1;
        float v = 0.0f;
        if (yy >= 0 && yy < 128 && xx >= 0 && xx < 128)
          v = x[((b*64 + cp)*128 + yy)*128 + xx];
        ((_Float16*)patch2)[l] = (_Float16)v;
      }
    }
    __syncthreads();

    float a0 = c1b, a1 = 0.f, a2 = 0.f, a3 = 0.f;
    int cbase = c * 292, pbase = q * 288;
    #pragma unroll 4
    for (int i2 = 0; i2 < 288; i2 += 4) {
      a0 = fdot2_(w1s[cbase + i2+0], patch2[pbase + i2+0], a0);
      a1 = fdot2_(w1s[cbase + i2+1], patch2[pbase + i2+1], a1);
      a2 = fdot2_(w1s[cbase + i2+2], patch2[pbase + i2+2], a2);
      a3 = fdot2_(w1s[cbase + i2+3], patch2[pbase + i2+3], a3);
    }
    float t1 = fmaxf((a0 + a1) + (a2 + a3), 0.0f);
    ((_Float16*)tl2)[q*64 + c] = (_Float16)t1;
    // tl2[q] written/read by same wave -> no barrier

    float acc2 = c2b;
    #pragma unroll
    for (int c2i = 0; c2i < 32; ++c2i)
      acc2 = fdot2_(w2p[c2i*64 + c], tl2[q*32 + c2i], acc2);
    int p = p0 + q;
    acc2 *= (float)point_mask[p];
    int k = p & 31, bn = p >> 5;
    dots_h[(k*NSEQ + bn)*64 + c] = (_Float16)acc2;   // time-major [k][bn][d]
  }
}

// ---------------------------------------------------------------------------
// Kernel 3: recurrent LSTMs (gate-permuted MFMA) + fused MLP head.
// 256 blocks x 512 threads (8 waves); 2 seqs/block.
// Wave w owns gate-tiles gt = 4w..4w+3; frags asm-pinned (non-remat).
// B operand: all 16 cols broadcast seq (col&1) -> no guarded reads,
// C cols 0,1 are the real sequences. In-register nonlinearity, 1 barrier/step.
// ---------------------------------------------------------------------------
__global__ __launch_bounds__(512)
__attribute__((amdgpu_waves_per_eu(2, 2)))
void lstm_head_kernel(const char* ws_ro, const float* b1, const float* W2,
                      const float* b2, float* out_kp) {
  const f16x8* feih   = (const f16x8*)(ws_ro + OFF_FEIH);
  const f16x8* fehh   = (const f16x8*)(ws_ro + OFF_FEHH);
  const f16x8* fdih   = (const f16x8*)(ws_ro + OFF_FDIH);
  const f16x8* fdhh   = (const f16x8*)(ws_ro + OFF_FDHH);
  const float* bias_e = (const float*)(ws_ro + OFF_BIAS_E);
  const float* bias_d = (const float*)(ws_ro + OFF_BIAS_D);
  const uint32_t* dots_u = (const uint32_t*)(ws_ro + OFF_DOTS);
  const uint32_t* W1h    = (const uint32_t*)(ws_ro + OFF_W1H);

  __shared__ __attribute__((aligned(16))) uint32_t xall[2][32][36];  //  9.2 KB
  __shared__ __attribute__((aligned(16))) uint32_t hb2[2][2][68];    //  2.2 KB
  __shared__ __attribute__((aligned(16))) uint32_t enc2[2][32][68];  // 17.4 KB
  __shared__ __attribute__((aligned(16))) uint32_t dech[2][32][68];  // 17.4 KB
  __shared__ float hidf[64][65];                                     // 16.6 KB

  int tid  = threadIdx.x;
  int lane = tid & 63, wave = tid >> 6;       // 8 waves
  int col  = lane & 15, lgrp = lane >> 4;
  int sb   = col & 1;                         // broadcast seq for B operand
  int bn0  = blockIdx.x * 2;
  int gtb  = wave * 4;

  // stage x for both seqs (2048 u32)
  for (int i = tid; i < 2048; i += 512) {
    int s = i >> 10, rem = i & 1023, t = rem >> 5, k2 = rem & 31;
    xall[s][t][k2] = dots_u[(t*NSEQ + bn0 + s)*32 + k2];
  }
  for (int i = tid; i < 2*2*68; i += 512) ((uint32_t*)hb2)[i] = 0u;

  // ---- encoder weights: 24 asm-pinned frags (96 VGPR) ----
  f16x8 fa[4][2], fb[4][4];
  float be[4][4];
  #pragma unroll
  for (int ti = 0; ti < 4; ++ti) {
    int gt = gtb + ti;
    #pragma unroll
    for (int kt = 0; kt < 2; ++kt) fa[ti][kt] = ldg_frag(&feih[(gt*2 + kt)*64 + lane]);
    #pragma unroll
    for (int kt = 0; kt < 4; ++kt) fb[ti][kt] = ldg_frag(&fehh[(gt*4 + kt)*64 + lane]);
    #pragma unroll
    for (int r = 0; r < 4; ++r) be[ti][r] = bias_e[r*128 + gt*4 + lgrp];
  }
  frag_fence();

  float cst[4] = {0.f, 0.f, 0.f, 0.f};
  int par = 0;
  __syncthreads();

  // ----------------- encoder -----------------
  for (int t = 0; t < 32; ++t) {
    f16x8 bx[2], bh[4];
    #pragma unroll
    for (int kt = 0; kt < 2; ++kt)
      bx[kt] = *(const f16x8*)&xall[sb][t][kt*16 + lgrp*4];
    #pragma unroll
    for (int kt = 0; kt < 4; ++kt)
      bh[kt] = *(const f16x8*)&hb2[par][sb][kt*16 + lgrp*4];
    #pragma unroll
    for (int ti = 0; ti < 4; ++ti) {
      f32x4 ac = {be[ti][0], be[ti][1], be[ti][2], be[ti][3]};
      #pragma unroll
      for (int kt = 0; kt < 2; ++kt)
        ac = __builtin_amdgcn_mfma_f32_16x16x32_f16(fa[ti][kt], bx[kt], ac, 0, 0, 0);
      #pragma unroll
      for (int kt = 0; kt < 4; ++kt)
        ac = __builtin_amdgcn_mfma_f32_16x16x32_f16(fb[ti][kt], bh[kt], ac, 0, 0, 0);
      float ig = sig_(ac[0]), fg = sig_(ac[1]);
      float gg = tanh_(ac[2]), og = sig_(ac[3]);
      cst[ti] = fg * cst[ti] + ig * gg;
      float hh = og * tanh_(cst[ti]);
      if (col < 2) {
        int u = (gtb + ti)*4 + lgrp;
        _Float16 hv = (_Float16)hh;
        ((_Float16*)&hb2[par^1][col][0])[u] = hv;
        ((_Float16*)&enc2[col][t][0])[u] = hv;
      }
    }
    __syncthreads();
    par ^= 1;
  }

  // ---- decoder weights: 32 asm-pinned frags (128 VGPR) ----
  f16x8 da[4][4], db[4][4];
  float bd[4][4];
  #pragma unroll
  for (int ti = 0; ti < 4; ++ti) {
    int gt = gtb + ti;
    #pragma unroll
    for (int kt = 0; kt < 4; ++kt) {
      da[ti][kt] = ldg_frag(&fdih[(gt*4 + kt)*64 + lane]);
      db[ti][kt] = ldg_frag(&fdhh[(gt*4 + kt)*64 + lane]);
    }
    #pragma unroll
    for (int r = 0; r < 4; ++r) bd[ti][r] = bias_d[r*128 + gt*4 + lgrp];
  }
  frag_fence();

  // ----------------- decoder -----------------
  for (int t = 0; t < 32; ++t) {
    f16x8 bx[4], bh[4];
    #pragma unroll
    for (int kt = 0; kt < 4; ++kt) {
      bx[kt] = *(const f16x8*)&enc2[sb][t][kt*16 + lgrp*4];
      bh[kt] = *(const f16x8*)&hb2[par][sb][kt*16 + lgrp*4];
    }
    #pragma unroll
    for (int ti = 0; ti < 4; ++ti) {
      f32x4 ac = {bd[ti][0], bd[ti][1], bd[ti][2], bd[ti][3]};
      #pragma unroll
      for (int kt = 0; kt < 4; ++kt)
        ac = __builtin_amdgcn_mfma_f32_16x16x32_f16(da[ti][kt], bx[kt], ac, 0, 0, 0);
      #pragma unroll
      for (int kt = 0; kt < 4; ++kt)
        ac = __builtin_amdgcn_mfma_f32_16x16x32_f16(db[ti][kt], bh[kt], ac, 0, 0, 0);
      float ig = sig_(ac[0]), fg = sig_(ac[1]);
      float gg = tanh_(ac[2]), og = sig_(ac[3]);
      cst[ti] = fg * cst[ti] + ig * gg;
      float hh = og * tanh_(cst[ti]);
      if (col < 2) {
        int u = (gtb + ti)*4 + lgrp;
        _Float16 hv = (_Float16)hh;
        ((_Float16*)&hb2[par^1][col][0])[u] = hv;
        ((_Float16*)&dech[col][t][0])[u] = hv;
      }
    }
    __syncthreads();
    par ^= 1;
  }

  // ----------------- fused head: relu(dec@W1.T+b1)@W2.T+b2 ----------------
  {
    int j = tid & 63, w = tid >> 6;   // 8 waves; rows w + 8m  (64 rows = 2s x 32t)
    float acc[8];
    #pragma unroll
    for (int m = 0; m < 8; ++m) acc[m] = b1[j];
    #pragma unroll 8
    for (int k = 0; k < 64; ++k) {
      uint32_t wv = W1h[k*64 + j];
      #pragma unroll
      for (int m = 0; m < 8; ++m) {
        int st = w + 8*m;
        acc[m] = fdot2_(wv, dech[st >> 5][st & 31][k], acc[m]);
      }
    }
    #pragma unroll
    for (int m = 0; m < 8; ++m)
      hidf[w + 8*m][j] = fmaxf(acc[m], 0.0f);
  }
  __syncthreads();
  if (tid < 128) {
    int r = tid >> 1, e = tid & 1;
    float a = b2[e];
    #pragma unroll 16
    for (int jj = 0; jj < 64; ++jj) a += W2[e*64 + jj] * hidf[r][jj];
    int s = r >> 5, t = r & 31;
    out_kp[((bn0 + s)*32 + t)*2 + e] = a;
  }
}

// ---------------------------------------------------------------------------
// Launch
// ---------------------------------------------------------------------------
extern "C" void kernel_launch(void* const* d_in, const int* in_sizes, int n_in,
                              void* d_out, int out_size, void* d_ws, size_t ws_size,
                              hipStream_t stream) {
  const float* x          = (const float*)d_in[0];
  const float* mask_point = (const float*)d_in[1];
  const int*   point_mask = (const int*)d_in[2];
  const float* conv1_w    = (const float*)d_in[3];
  const float* conv1_b    = (const float*)d_in[4];
  const float* conv2_w    = (const float*)d_in[5];
  const float* conv2_b    = (const float*)d_in[6];
  const float* Wih_e      = (const float*)d_in[7];
  const float* Whh_e      = (const float*)d_in[8];
  const float* bih_e      = (const float*)d_in[9];
  const float* bhh_e      = (const float*)d_in[10];
  const float* Wih_d      = (const float*)d_in[11];
  const float* Whh_d      = (const float*)d_in[12];
  const float* bih_d      = (const float*)d_in[13];
  const float* bhh_d      = (const float*)d_in[14];
  const float* W1         = (const float*)d_in[15];
  const float* b1         = (const float*)d_in[16];
  const float* W2         = (const float*)d_in[17];
  const float* b2         = (const float*)d_in[18];

  float* out = (float*)d_out;
  char*  ws  = (char*)d_ws;

  const bool use_xt = (ws_size >= WS_NEED_XT);

  prep_kernel<<<(PREP_TOTAL + 255)/256, 256, 0, stream>>>(
      Wih_e, Whh_e, bih_e, bhh_e, Wih_d, Whh_d, bih_d, bhh_d,
      conv1_w, conv2_w, W1, mask_point, out + 32768, (int*)(ws + OFF_FLAT),
      ws, use_xt ? 1 : 0);

  if (use_xt) {
    transpose_kernel<<<1024, 256, 0, stream>>>(x, (uint32_t*)(ws + OFF_XT));
    conv_gather_kernel<1><<<512, 256, 0, stream>>>(
        x, (const uint32_t*)(ws + OFF_XT), point_mask, conv1_b, conv2_b,
        ws, (_Float16*)(ws + OFF_DOTS), (const int*)(ws + OFF_FLAT));
  } else {
    conv_gather_kernel<0><<<512, 256, 0, stream>>>(
        x, nullptr, point_mask, conv1_b, conv2_b,
        ws, (_Float16*)(ws + OFF_DOTS), (const int*)(ws + OFF_FLAT));
  }

  lstm_head_kernel<<<256, 512, 0, stream>>>(ws, b1, W2, b2, out);
}

// Round 10
// 188.805 us; speedup vs baseline: 1.0416x; 1.0269x over previous
//
#include <hip/hip_runtime.h>
#include <stdint.h>

// ---------------------------------------------------------------------------
// Problem constants
// ---------------------------------------------------------------------------
#define NSEQ 512        // B*N
#define HIDN 128

// ws byte offsets
#define OFF_BIAS_E 0                            // 512 f32
#define OFF_BIAS_D 2048                         // 512 f32
#define OFF_W1P    4096                         // conv w1 f16 pairs [288][64]
#define OFF_W2P    77824                        // conv w2 f16 pairs [32][64]
#define OFF_FLAT   86016                        // [16384] int
#define OFF_W1H    151552                       // head W1 f16 pairs [64][64]
#define OFF_FEIH   167936                       // enc Wih frags (32gt x 2kt), 64 KB
#define OFF_FEHH   233472                       // enc Whh frags (32gt x 4kt), 128 KB
#define OFF_FDIH   364544                       // dec Wih frags, 128 KB
#define OFF_FDHH   495616                       // dec Whh frags, 128 KB
#define OFF_DOTS   (1024*1024)                  // [32][512][64] f16 = 2 MB
#define OFF_XT     (4*1024*1024)                // xT [16][128][128][64] f16 = 33.5 MB
#define WS_NEED_XT ((size_t)(4*1024*1024) + (size_t)16*128*128*64*2 + 1024)

typedef _Float16 h2f __attribute__((ext_vector_type(2)));
typedef _Float16 f16x8 __attribute__((ext_vector_type(8)));
typedef float    f32x4 __attribute__((ext_vector_type(4)));

static __device__ __forceinline__ h2f u2h(uint32_t u) {
  union { uint32_t u; h2f h; } v; v.u = u; return v.h;
}

#if __has_builtin(__builtin_amdgcn_fdot2)
static __device__ __forceinline__ float fdot2_(uint32_t a, uint32_t b, float c) {
  return __builtin_amdgcn_fdot2(u2h(a), u2h(b), c, false);
}
#else
static __device__ __forceinline__ float fdot2_(uint32_t a, uint32_t b, float c) {
  h2f x = u2h(a), y = u2h(b);
  return c + (float)x.x * (float)y.x + (float)x.y * (float)y.y;
}
#endif

static __device__ __forceinline__ uint32_t packh(float a, float b) {
  union { _Float16 h[2]; uint32_t u; } v;
  v.h[0] = (_Float16)a; v.h[1] = (_Float16)b; return v.u;
}
static __device__ __forceinline__ float sig_(float x) {
  return 1.0f / (1.0f + __expf(-x));
}
static __device__ __forceinline__ float tanh_(float x) {
  return 1.0f - 2.0f / (1.0f + __expf(2.0f * x));
}

// Volatile-asm fragment load: value is asm-produced -> compiler CANNOT
// rematerialize it; with budget >= live set it must stay in registers.
static __device__ __forceinline__ f16x8 ldg_frag(const f16x8* p) {
  f16x8 r;
  asm volatile("global_load_dwordx4 %0, %1, off" : "=v"(r) : "v"(p));
  return r;
}
static __device__ __forceinline__ void frag_fence() {
  asm volatile("s_waitcnt vmcnt(0)" ::: "memory");
  __builtin_amdgcn_sched_barrier(0);
}

// ---------------------------------------------------------------------------
// Kernel 0: weight prep + point math.
// MFMA A-frag, 16x16x32_f16: lane l, j in 0..7: A[row=l&15][k=(l>>4)*8+j].
// GATE PERMUTATION: tile gt, row16 -> W row g = (row16&3)*128 + gt*4 + (row16>>2)
// k map (must match B build): k = kt*32 + (l>>4)*8 + 2*j2 (+0,+1).
// ---------------------------------------------------------------------------
__global__ __launch_bounds__(256) void prep_kernel(
    const float* Wih_e, const float* Whh_e,
    const float* bih_e, const float* bhh_e,
    const float* Wih_d, const float* Whh_d,
    const float* bih_d, const float* bhh_d,
    const float* w1, const float* w2, const float* W1,
    const float* mask_point, float* out_gt, int* flat,
    char* ws, int w1_order) {
  float*    bias_e = (float*)(ws + OFF_BIAS_E);
  float*    bias_d = (float*)(ws + OFF_BIAS_D);
  uint32_t* w1p    = (uint32_t*)(ws + OFF_W1P);
  uint32_t* w2p    = (uint32_t*)(ws + OFF_W2P);
  uint32_t* W1h    = (uint32_t*)(ws + OFF_W1H);

  int idx = blockIdx.x * 256 + threadIdx.x;
  if (idx < 512) { bias_e[idx] = bih_e[idx] + bhh_e[idx]; return; }
  idx -= 512;
  if (idx < 512) { bias_d[idx] = bih_d[idx] + bhh_d[idx]; return; }
  idx -= 512;
  if (idx < 288*64) {                             // conv w1 pairs [i2][c]
    int i2 = idx >> 6, c = idx & 63;
    if (w1_order) {
      int tap = i2 >> 5, cin = (i2 & 31) * 2;     // i2 = tap*32 + c2
      w1p[idx] = packh(w1[c*576 + cin*9 + tap], w1[c*576 + (cin+1)*9 + tap]);
    } else {
      w1p[idx] = packh(w1[c*576 + 2*i2], w1[c*576 + 2*i2 + 1]);
    }
    return;
  }
  idx -= 288*64;
  if (idx < 32*64) {                              // conv w2 pairs [c2][d]
    int c2 = idx >> 6, d = idx & 63;
    w2p[idx] = packh(w2[d*64 + 2*c2], w2[d*64 + 2*c2 + 1]);
    return;
  }
  idx -= 32*64;
  if (idx < 64*64) {                              // head W1 pairs [k2][j]
    int k2 = idx >> 6, j = idx & 63;
    W1h[idx] = packh(W1[j*128 + 2*k2], W1[j*128 + 2*k2 + 1]);
    return;
  }
  idx -= 64*64;
  if (idx < 16384) {                              // feih: 32gt x 2kt, k<64
    int j2 = idx & 3, lane = (idx >> 2) & 63, kt = (idx >> 8) & 1, gt = idx >> 9;
    int row16 = lane & 15;
    int g = (row16 & 3)*128 + gt*4 + (row16 >> 2);
    int k = kt*32 + (lane >> 4)*8 + 2*j2;
    ((uint32_t*)(ws + OFF_FEIH))[idx] = packh(Wih_e[g*64 + k], Wih_e[g*64 + k + 1]);
    return;
  }
  idx -= 16384;
  if (idx < 3*32768) {                            // fehh / fdih / fdhh: 32gt x 4kt
    int which = idx >> 15, r = idx & 32767;
    int j2 = r & 3, lane = (r >> 2) & 63, kt = (r >> 8) & 3, gt = r >> 10;
    int row16 = lane & 15;
    int g = (row16 & 3)*128 + gt*4 + (row16 >> 2);
    int k = kt*32 + (lane >> 4)*8 + 2*j2;
    const float* W = (which == 0) ? Whh_e : ((which == 1) ? Wih_d : Whh_d);
    uint32_t* dst = (uint32_t*)(ws + ((which == 0) ? OFF_FEHH :
                                      (which == 1) ? OFF_FDIH : OFF_FDHH));
    dst[r] = packh(W[g*128 + k], W[g*128 + k + 1]);
    return;
  }
  idx -= 3*32768;
  if (idx < 16384) {                              // point math -> gt + flat
    float mx = mask_point[idx*2 + 0];
    float my = mask_point[idx*2 + 1];
    float fx = fminf(mx * 0.25f, 127.0f);
    float fy = fminf(my * 0.25f, 127.0f);
    out_gt[idx*2 + 0] = fx * 4.0f;
    out_gt[idx*2 + 1] = fy * 4.0f;
    flat[idx] = (int)(__fmaf_rn(fy, 128.0f, fx)); // fy*128 exact
    return;
  }
}
#define PREP_TOTAL (512 + 512 + 288*64 + 32*64 + 64*64 + 16384 + 3*32768 + 16384)

// ---------------------------------------------------------------------------
// Kernel T: x [16][64][128][128] f32 -> xT [16][128][128][64] f16 (NHWC)
// ---------------------------------------------------------------------------
__global__ __launch_bounds__(256, 2) void transpose_kernel(
    const float* x, uint32_t* xT32) {
  __shared__ float lds[64][257];
  int bid = blockIdx.x;           // 1024 = 16 b x 16 yt x 4 xt
  int xt = bid & 3, yt = (bid >> 2) & 15, b = bid >> 6;
  int x0 = xt * 32, y0 = yt * 8;
  int tx = threadIdx.x & 31, ty = threadIdx.x >> 5;
  #pragma unroll 8
  for (int c = 0; c < 64; ++c)
    lds[c][ty*32 + tx] = x[((b*64 + c)*128 + (y0 + ty))*128 + (x0 + tx)];
  __syncthreads();
  #pragma unroll 8
  for (int r = 0; r < 32; ++r) {
    int i = threadIdx.x + 256*r;    // i = pos*32 + c2
    int c2 = i & 31, pos = i >> 5;
    int yy = pos >> 5, xx = pos & 31;
    float lo = lds[2*c2][yy*32 + xx], hi = lds[2*c2 + 1][yy*32 + xx];
    xT32[((b*128 + y0 + yy)*128 + (x0 + xx))*32 + c2] = packh(lo, hi);
  }
}

// ---------------------------------------------------------------------------
// Kernel 2: fused gathered conv (3x3 -> ReLU -> 1x1) at points, 4 pts/group
// ---------------------------------------------------------------------------
template <int MODE>
__global__ __launch_bounds__(256, 2) void conv_gather_kernel(
    const float* x, const uint32_t* xT32, const int* point_mask,
    const float* conv1_b, const float* conv2_b,
    const char* ws_ro, _Float16* dots_h, const int* flat) {
  __shared__ uint32_t w1s[64*292];    // 74752 B (292: 16B-aligned rows)
  __shared__ uint32_t patch2[4*288];  //  4608 B
  __shared__ uint32_t tl2[4*32];      //   512 B

  const uint32_t* w1p = (const uint32_t*)(ws_ro + OFF_W1P);
  const uint32_t* w2p = (const uint32_t*)(ws_ro + OFF_W2P);
  int tid = threadIdx.x;
  for (int i = tid; i < 288*64; i += 256) {
    int i2 = i >> 6, cc = i & 63;
    w1s[cc*292 + i2] = w1p[i];
  }

  int q = tid >> 6, c = tid & 63;
  float c1b = conv1_b[c], c2b = conv2_b[c];

  for (int g = 0; g < 8; ++g) {
    int p0 = blockIdx.x * 32 + g * 4;
    __syncthreads();
    if (MODE == 1) {
      #pragma unroll
      for (int r = 0; r < 5; ++r) {  // 1152 u32 = 4 pts x 288
        int u = tid + 256*r;
        if (u < 1152) {
          int slot = u / 288, w = u - slot*288;
          int tap = w >> 5, c2i = w & 31;
          int p = p0 + slot;
          int fl = flat[p];
          int hh = fl >> 7, ww = fl & 127;
          int b = p >> 10;
          int dy = tap / 3, dx = tap - dy*3;
          int yy = hh + dy - 1, xx = ww + dx - 1;
          uint32_t v = 0u;
          if (yy >= 0 && yy < 128 && xx >= 0 && xx < 128)
            v = xT32[((b*128 + yy)*128 + xx)*32 + c2i];
          patch2[slot*288 + w] = v;
        }
      }
    } else {
      #pragma unroll
      for (int r = 0; r < 9; ++r) {  // 2304 halves = 4 pts x 576
        int l = tid + 256*r;
        int slot = l / 576;
        int within = l - slot*576;
        int cp = within / 9;
        int tap = within - cp*9;
        int p = p0 + slot;
        int fl = flat[p];
        int hh = fl >> 7, ww = fl & 127;
        int b = p >> 10;
        int yy = hh + tap/3 - 1, xx = ww + tap%3 - 1;
        float v = 0.0f;
        if (yy >= 0 && yy < 128 && xx >= 0 && xx < 128)
          v = x[((b*64 + cp)*128 + yy)*128 + xx];
        ((_Float16*)patch2)[l] = (_Float16)v;
      }
    }
    __syncthreads();

    float a0 = c1b, a1 = 0.f, a2 = 0.f, a3 = 0.f;
    int cbase = c * 292, pbase = q * 288;
    #pragma unroll 4
    for (int i2 = 0; i2 < 288; i2 += 4) {
      a0 = fdot2_(w1s[cbase + i2+0], patch2[pbase + i2+0], a0);
      a1 = fdot2_(w1s[cbase + i2+1], patch2[pbase + i2+1], a1);
      a2 = fdot2_(w1s[cbase + i2+2], patch2[pbase + i2+2], a2);
      a3 = fdot2_(w1s[cbase + i2+3], patch2[pbase + i2+3], a3);
    }
    float t1 = fmaxf((a0 + a1) + (a2 + a3), 0.0f);
    ((_Float16*)tl2)[q*64 + c] = (_Float16)t1;
    // tl2[q] written/read by same wave -> no barrier

    float acc2 = c2b;
    #pragma unroll
    for (int c2i = 0; c2i < 32; ++c2i)
      acc2 = fdot2_(w2p[c2i*64 + c], tl2[q*32 + c2i], acc2);
    int p = p0 + q;
    acc2 *= (float)point_mask[p];
    int k = p & 31, bn = p >> 5;
    dots_h[(k*NSEQ + bn)*64 + c] = (_Float16)acc2;   // time-major [k][bn][d]
  }
}

// ---------------------------------------------------------------------------
// Kernel 3: recurrent LSTMs (gate-permuted MFMA) + fused MLP head.
// 256 blocks x 1024 threads (16 waves); 2 seqs/block.
// Wave w owns gate-tiles gt = 2w, 2w+1: enc 12 frags (48 VGPR), dec 16 frags
// (64 VGPR) -- BOTH phases fit arch VGPRs (the ≤16-frag threshold observed
// across R5/R8/R9), asm-pinned so they cannot be rematerialized or dumped.
// waves_per_eu(4,4): budget exactly 128 -> no AGPR-parking headroom.
// B operand: broadcast seq (col&1); C cols 0,1 are the real sequences.
// In-register nonlinearity (20 trans/thread), 1 barrier/step.
// ---------------------------------------------------------------------------
__global__ __launch_bounds__(1024)
__attribute__((amdgpu_waves_per_eu(4, 4)))
void lstm_head_kernel(const char* ws_ro, const float* b1, const float* W2,
                      const float* b2, float* out_kp) {
  const f16x8* feih   = (const f16x8*)(ws_ro + OFF_FEIH);
  const f16x8* fehh   = (const f16x8*)(ws_ro + OFF_FEHH);
  const f16x8* fdih   = (const f16x8*)(ws_ro + OFF_FDIH);
  const f16x8* fdhh   = (const f16x8*)(ws_ro + OFF_FDHH);
  const float* bias_e = (const float*)(ws_ro + OFF_BIAS_E);
  const float* bias_d = (const float*)(ws_ro + OFF_BIAS_D);
  const uint32_t* dots_u = (const uint32_t*)(ws_ro + OFF_DOTS);
  const uint32_t* W1h    = (const uint32_t*)(ws_ro + OFF_W1H);

  __shared__ __attribute__((aligned(16))) uint32_t xall[2][32][36];  //  9.2 KB
  __shared__ __attribute__((aligned(16))) uint32_t hb2[2][2][68];    //  2.2 KB
  __shared__ __attribute__((aligned(16))) uint32_t enc2[2][32][68];  // 17.4 KB
  __shared__ __attribute__((aligned(16))) uint32_t dech[2][32][68];  // 17.4 KB
  __shared__ float hidf[64][65];                                     // 16.6 KB

  int tid  = threadIdx.x;
  int lane = tid & 63, wave = tid >> 6;       // 16 waves
  int col  = lane & 15, lgrp = lane >> 4;
  int sb   = col & 1;                         // broadcast seq for B operand
  int bn0  = blockIdx.x * 2;
  int gtb  = wave * 2;                        // 2 gate-tiles per wave

  // stage x for both seqs (2048 u32)
  for (int i = tid; i < 2048; i += 1024) {
    int s = i >> 10, rem = i & 1023, t = rem >> 5, k2 = rem & 31;
    xall[s][t][k2] = dots_u[(t*NSEQ + bn0 + s)*32 + k2];
  }
  if (tid < 2*2*68) ((uint32_t*)hb2)[tid] = 0u;

  // ---- encoder weights: 12 asm-pinned frags (48 VGPR) ----
  f16x8 fa[2][2], fb[2][4];
  float be[2][4];
  #pragma unroll
  for (int ti = 0; ti < 2; ++ti) {
    int gt = gtb + ti;
    #pragma unroll
    for (int kt = 0; kt < 2; ++kt) fa[ti][kt] = ldg_frag(&feih[(gt*2 + kt)*64 + lane]);
    #pragma unroll
    for (int kt = 0; kt < 4; ++kt) fb[ti][kt] = ldg_frag(&fehh[(gt*4 + kt)*64 + lane]);
    #pragma unroll
    for (int r = 0; r < 4; ++r) be[ti][r] = bias_e[r*128 + gt*4 + lgrp];
  }
  frag_fence();

  float cst[2] = {0.f, 0.f};
  int par = 0;
  __syncthreads();

  // ----------------- encoder -----------------
  for (int t = 0; t < 32; ++t) {
    f16x8 bx[2], bh[4];
    #pragma unroll
    for (int kt = 0; kt < 2; ++kt)
      bx[kt] = *(const f16x8*)&xall[sb][t][kt*16 + lgrp*4];
    #pragma unroll
    for (int kt = 0; kt < 4; ++kt)
      bh[kt] = *(const f16x8*)&hb2[par][sb][kt*16 + lgrp*4];
    #pragma unroll
    for (int ti = 0; ti < 2; ++ti) {
      f32x4 ac = {be[ti][0], be[ti][1], be[ti][2], be[ti][3]};
      #pragma unroll
      for (int kt = 0; kt < 2; ++kt)
        ac = __builtin_amdgcn_mfma_f32_16x16x32_f16(fa[ti][kt], bx[kt], ac, 0, 0, 0);
      #pragma unroll
      for (int kt = 0; kt < 4; ++kt)
        ac = __builtin_amdgcn_mfma_f32_16x16x32_f16(fb[ti][kt], bh[kt], ac, 0, 0, 0);
      float ig = sig_(ac[0]), fg = sig_(ac[1]);
      float gg = tanh_(ac[2]), og = sig_(ac[3]);
      cst[ti] = fg * cst[ti] + ig * gg;
      float hh = og * tanh_(cst[ti]);
      if (col < 2) {
        int u = (gtb + ti)*4 + lgrp;
        _Float16 hv = (_Float16)hh;
        ((_Float16*)&hb2[par^1][col][0])[u] = hv;
        ((_Float16*)&enc2[col][t][0])[u] = hv;
      }
    }
    __syncthreads();
    par ^= 1;
  }

  // ---- decoder weights: 16 asm-pinned frags (64 VGPR) ----
  f16x8 da[2][4], db[2][4];
  float bd[2][4];
  #pragma unroll
  for (int ti = 0; ti < 2; ++ti) {
    int gt = gtb + ti;
    #pragma unroll
    for (int kt = 0; kt < 4; ++kt) {
      da[ti][kt] = ldg_frag(&fdih[(gt*4 + kt)*64 + lane]);
      db[ti][kt] = ldg_frag(&fdhh[(gt*4 + kt)*64 + lane]);
    }
    #pragma unroll
    for (int r = 0; r < 4; ++r) bd[ti][r] = bias_d[r*128 + gt*4 + lgrp];
  }
  frag_fence();

  // ----------------- decoder -----------------
  for (int t = 0; t < 32; ++t) {
    f16x8 bx[4], bh[4];
    #pragma unroll
    for (int kt = 0; kt < 4; ++kt) {
      bx[kt] = *(const f16x8*)&enc2[sb][t][kt*16 + lgrp*4];
      bh[kt] = *(const f16x8*)&hb2[par][sb][kt*16 + lgrp*4];
    }
    #pragma unroll
    for (int ti = 0; ti < 2; ++ti) {
      f32x4 ac = {bd[ti][0], bd[ti][1], bd[ti][2], bd[ti][3]};
      #pragma unroll
      for (int kt = 0; kt < 4; ++kt)
        ac = __builtin_amdgcn_mfma_f32_16x16x32_f16(da[ti][kt], bx[kt], ac, 0, 0, 0);
      #pragma unroll
      for (int kt = 0; kt < 4; ++kt)
        ac = __builtin_amdgcn_mfma_f32_16x16x32_f16(db[ti][kt], bh[kt], ac, 0, 0, 0);
      float ig = sig_(ac[0]), fg = sig_(ac[1]);
      float gg = tanh_(ac[2]), og = sig_(ac[3]);
      cst[ti] = fg * cst[ti] + ig * gg;
      float hh = og * tanh_(cst[ti]);
      if (col < 2) {
        int u = (gtb + ti)*4 + lgrp;
        _Float16 hv = (_Float16)hh;
        ((_Float16*)&hb2[par^1][col][0])[u] = hv;
        ((_Float16*)&dech[col][t][0])[u] = hv;
      }
    }
    __syncthreads();
    par ^= 1;
  }

  // ----------------- fused head: relu(dec@W1.T+b1)@W2.T+b2 ----------------
  {
    int j = tid & 63, w = tid >> 6;   // 16 waves; rows w + 16*m (64 = 2s x 32t)
    float acc[4];
    #pragma unroll
    for (int m = 0; m < 4; ++m) acc[m] = b1[j];
    #pragma unroll 8
    for (int k = 0; k < 64; ++k) {
      uint32_t wv = W1h[k*64 + j];
      #pragma unroll
      for (int m = 0; m < 4; ++m) {
        int st = w + 16*m;
        acc[m] = fdot2_(wv, dech[st >> 5][st & 31][k], acc[m]);
      }
    }
    #pragma unroll
    for (int m = 0; m < 4; ++m)
      hidf[w + 16*m][j] = fmaxf(acc[m], 0.0f);
  }
  __syncthreads();
  if (tid < 128) {
    int r = tid >> 1, e = tid & 1;
    float a = b2[e];
    #pragma unroll 16
    for (int jj = 0; jj < 64; ++jj) a += W2[e*64 + jj] * hidf[r][jj];
    int s = r >> 5, t = r & 31;
    out_kp[((bn0 + s)*32 + t)*2 + e] = a;
  }
}

// ---------------------------------------------------------------------------
// Launch
// ---------------------------------------------------------------------------
extern "C" void kernel_launch(void* const* d_in, const int* in_sizes, int n_in,
                              void* d_out, int out_size, void* d_ws, size_t ws_size,
                              hipStream_t stream) {
  const float* x          = (const float*)d_in[0];
  const float* mask_point = (const float*)d_in[1];
  const int*   point_mask = (const int*)d_in[2];
  const float* conv1_w    = (const float*)d_in[3];
  const float* conv1_b    = (const float*)d_in[4];
  const float* conv2_w    = (const float*)d_in[5];
  const float* conv2_b    = (const float*)d_in[6];
  const float* Wih_e      = (const float*)d_in[7];
  const float* Whh_e      = (const float*)d_in[8];
  const float* bih_e      = (const float*)d_in[9];
  const float* bhh_e      = (const float*)d_in[10];
  const float* Wih_d      = (const float*)d_in[11];
  const float* Whh_d      = (const float*)d_in[12];
  const float* bih_d      = (const float*)d_in[13];
  const float* bhh_d      = (const float*)d_in[14];
  const float* W1         = (const float*)d_in[15];
  const float* b1         = (const float*)d_in[16];
  const float* W2         = (const float*)d_in[17];
  const float* b2         = (const float*)d_in[18];

  float* out = (float*)d_out;
  char*  ws  = (char*)d_ws;

  const bool use_xt = (ws_size >= WS_NEED_XT);

  prep_kernel<<<(PREP_TOTAL + 255)/256, 256, 0, stream>>>(
      Wih_e, Whh_e, bih_e, bhh_e, Wih_d, Whh_d, bih_d, bhh_d,
      conv1_w, conv2_w, W1, mask_point, out + 32768, (int*)(ws + OFF_FLAT),
      ws, use_xt ? 1 : 0);

  if (use_xt) {
    transpose_kernel<<<1024, 256, 0, stream>>>(x, (uint32_t*)(ws + OFF_XT));
    conv_gather_kernel<1><<<512, 256, 0, stream>>>(
        x, (const uint32_t*)(ws + OFF_XT), point_mask, conv1_b, conv2_b,
        ws, (_Float16*)(ws + OFF_DOTS), (const int*)(ws + OFF_FLAT));
  } else {
    conv_gather_kernel<0><<<512, 256, 0, stream>>>(
        x, nullptr, point_mask, conv1_b, conv2_b,
        ws, (_Float16*)(ws + OFF_DOTS), (const int*)(ws + OFF_FLAT));
  }

  lstm_head_kernel<<<256, 1024, 0, stream>>>(ws, b1, W2, b2, out);
}

// Round 11
// 162.589 us; speedup vs baseline: 1.2095x; 1.1612x over previous
//
#include <hip/hip_runtime.h>
#include <stdint.h>

// ---------------------------------------------------------------------------
// Problem constants
// ---------------------------------------------------------------------------
#define NSEQ 512        // B*N
#define HIDN 128

// ws byte offsets
#define OFF_PWIH_E 0                            // 32*512*4 = 65536 (gx weights)
#define OFF_BIAS_E 65536                        // 512 f32
#define OFF_BIAS_D 67584                        // 512 f32
#define OFF_W1P    69632                        // conv w1 f16 pairs [288][64]
#define OFF_W2P    143360                       // conv w2 f16 pairs [32][64]
#define OFF_FLAT   151552                       // [16384] int
#define OFF_W1H    217088                       // head W1 f16 pairs [64][64]
#define OFF_FEHH   233472                       // enc Whh f16 frags, 128 KB
#define OFF_FDIH8  364544                       // dec Wih fp8 frags, 64 KB
#define OFF_FDHH8  430080                       // dec Whh fp8 frags, 64 KB
#define OFF_DOTS   (1024*1024)                  // [32][512][64] f16 = 2 MB
#define OFF_GX_FB  (3*1024*1024)                // fallback gx area
#define OFF_XT     (4*1024*1024)                // xT f16 = 33.5 MB (gx overlays)
#define WS_NEED_XT ((size_t)(4*1024*1024) + (size_t)16*128*128*64*2 + 1024)

typedef _Float16 h2f __attribute__((ext_vector_type(2)));
typedef _Float16 f16x8 __attribute__((ext_vector_type(8)));
typedef float    f32x4 __attribute__((ext_vector_type(4)));

static __device__ __forceinline__ h2f u2h(uint32_t u) {
  union { uint32_t u; h2f h; } v; v.u = u; return v.h;
}

#if __has_builtin(__builtin_amdgcn_fdot2)
static __device__ __forceinline__ float fdot2_(uint32_t a, uint32_t b, float c) {
  return __builtin_amdgcn_fdot2(u2h(a), u2h(b), c, false);
}
#else
static __device__ __forceinline__ float fdot2_(uint32_t a, uint32_t b, float c) {
  h2f x = u2h(a), y = u2h(b);
  return c + (float)x.x * (float)y.x + (float)x.y * (float)y.y;
}
#endif

static __device__ __forceinline__ uint32_t packh(float a, float b) {
  union { _Float16 h[2]; uint32_t u; } v;
  v.h[0] = (_Float16)a; v.h[1] = (_Float16)b; return v.u;
}
static __device__ __forceinline__ float sig_(float x) {
  return 1.0f / (1.0f + __expf(-x));
}
static __device__ __forceinline__ float tanh_(float x) {
  return 1.0f - 2.0f / (1.0f + __expf(2.0f * x));
}

// ---- fp8 e4m3fn helpers ----------------------------------------------------
static __device__ __forceinline__ uint32_t f2e4m3_sw(float f) {
  union { float f; uint32_t u; } v; v.f = f;
  uint32_t s = (v.u >> 24) & 0x80u;
  float af = fabsf(f);
  if (af == 0.0f) return s;
  if (af >= 448.0f) return s | 0x7Eu;
  int e; float m = frexpf(af, &e);      // af = m*2^e, m in [0.5,1)
  int E = e + 6;                         // 1.xxx*2^(e-1), bias 7
  float mant = m * 2.0f - 1.0f;
  int mm = (int)(mant * 8.0f + 0.5f);
  if (mm == 8) { mm = 0; ++E; }
  if (E < 1) {                           // subnormal: step 2^-9
    int sm = (int)(af * 512.0f + 0.5f);
    return s | (uint32_t)(sm > 7 ? 7 : sm);
  }
  if (E > 15) return s | 0x7Eu;
  return s | ((uint32_t)E << 3) | (uint32_t)mm;
}
static __device__ __forceinline__ uint32_t pk4_fp8(float a, float b, float c, float d) {
#if __has_builtin(__builtin_amdgcn_cvt_pk_fp8_f32)
  int r = __builtin_amdgcn_cvt_pk_fp8_f32(a, b, 0, false);
  r = __builtin_amdgcn_cvt_pk_fp8_f32(c, d, r, true);
  return (uint32_t)r;
#else
  return f2e4m3_sw(a) | (f2e4m3_sw(b) << 8) | (f2e4m3_sw(c) << 16) | (f2e4m3_sw(d) << 24);
#endif
}
static __device__ __forceinline__ uint8_t f8_(float v) {
#if __has_builtin(__builtin_amdgcn_cvt_pk_fp8_f32)
  return (uint8_t)(__builtin_amdgcn_cvt_pk_fp8_f32(v, 0.f, 0, false) & 0xFF);
#else
  return (uint8_t)f2e4m3_sw(v);
#endif
}
static __device__ __forceinline__ long u2l(uint2 v) {
  union { uint2 v; long l; } x; x.v = v; return x.l;
}
// pinned 8B load (asm-produced -> non-rematerializable)
static __device__ __forceinline__ uint2 ldg_frag8(const uint2* p) {
  uint2 r;
  asm volatile("global_load_dwordx2 %0, %1, off" : "=v"(r) : "v"(p));
  return r;
}
static __device__ __forceinline__ void frag_fence() {
  asm volatile("s_waitcnt vmcnt(0)" ::: "memory");
  __builtin_amdgcn_sched_barrier(0);
}

// ---------------------------------------------------------------------------
// Kernel 0: weight prep + point math.
// f16 A-frag (16x16x32): lane l holds A[row=l&15][k=(l>>4)*8+j], j=0..7.
// PLAIN tiling (R5): g = gt*16 + (l&15); k = kt*32 + ((l>>4)&3)*8 + ...
// fp8 frags use the same map with 8 fp8 bytes (2 VGPRs).
// ---------------------------------------------------------------------------
__global__ __launch_bounds__(256) void prep_kernel(
    const float* Wih_e, const float* Whh_e,
    const float* bih_e, const float* bhh_e,
    const float* Wih_d, const float* Whh_d,
    const float* bih_d, const float* bhh_d,
    const float* w1, const float* w2, const float* W1,
    const float* mask_point, float* out_gt, int* flat,
    char* ws, int w1_order) {
  uint32_t* pWih_e = (uint32_t*)(ws + OFF_PWIH_E);
  float*    bias_e = (float*)(ws + OFF_BIAS_E);
  float*    bias_d = (float*)(ws + OFF_BIAS_D);
  uint32_t* w1p    = (uint32_t*)(ws + OFF_W1P);
  uint32_t* w2p    = (uint32_t*)(ws + OFF_W2P);
  uint32_t* W1h    = (uint32_t*)(ws + OFF_W1H);

  int idx = blockIdx.x * 256 + threadIdx.x;
  if (idx < 32*512) {                             // pWih_e [k2][g] (for gx)
    int k2 = idx >> 9, g = idx & 511;
    pWih_e[idx] = packh(Wih_e[g*64 + 2*k2], Wih_e[g*64 + 2*k2 + 1]);
    return;
  }
  idx -= 32*512;
  if (idx < 512) { bias_e[idx] = bih_e[idx] + bhh_e[idx]; return; }
  idx -= 512;
  if (idx < 512) { bias_d[idx] = bih_d[idx] + bhh_d[idx]; return; }
  idx -= 512;
  if (idx < 288*64) {                             // conv w1 pairs [i2][c]
    int i2 = idx >> 6, c = idx & 63;
    if (w1_order) {
      int tap = i2 >> 5, cin = (i2 & 31) * 2;     // i2 = tap*32 + c2
      w1p[idx] = packh(w1[c*576 + cin*9 + tap], w1[c*576 + (cin+1)*9 + tap]);
    } else {
      w1p[idx] = packh(w1[c*576 + 2*i2], w1[c*576 + 2*i2 + 1]);
    }
    return;
  }
  idx -= 288*64;
  if (idx < 32*64) {                              // conv w2 pairs [c2][d]
    int c2 = idx >> 6, d = idx & 63;
    w2p[idx] = packh(w2[d*64 + 2*c2], w2[d*64 + 2*c2 + 1]);
    return;
  }
  idx -= 32*64;
  if (idx < 64*64) {                              // head W1 pairs [k2][j]
    int k2 = idx >> 6, j = idx & 63;
    W1h[idx] = packh(W1[j*128 + 2*k2], W1[j*128 + 2*k2 + 1]);
    return;
  }
  idx -= 64*64;
  if (idx < 32768) {                              // fehh f16 frags (R5 map)
    int j2 = idx & 3, lane = (idx >> 2) & 63, kt = (idx >> 8) & 3, gt = idx >> 10;
    int g = gt*16 + (lane & 15);
    int k = kt*32 + ((lane >> 4) & 3)*8 + 2*j2;
    ((uint32_t*)(ws + OFF_FEHH))[idx] = packh(Whh_e[g*128 + k], Whh_e[g*128 + k + 1]);
    return;
  }
  idx -= 32768;
  if (idx < 16384) {                              // fdih8 fp8 frags
    int half = idx & 1, lane = (idx >> 1) & 63, kt = (idx >> 7) & 3, gt = idx >> 9;
    int g = gt*16 + (lane & 15);
    int kb = kt*32 + ((lane >> 4) & 3)*8 + half*4;
    const float* W = Wih_d;
    ((uint32_t*)(ws + OFF_FDIH8))[(((gt*4 + kt)*64 + lane) << 1) | half] =
        pk4_fp8(W[g*128 + kb], W[g*128 + kb + 1], W[g*128 + kb + 2], W[g*128 + kb + 3]);
    return;
  }
  idx -= 16384;
  if (idx < 16384) {                              // fdhh8 fp8 frags
    int half = idx & 1, lane = (idx >> 1) & 63, kt = (idx >> 7) & 3, gt = idx >> 9;
    int g = gt*16 + (lane & 15);
    int kb = kt*32 + ((lane >> 4) & 3)*8 + half*4;
    const float* W = Whh_d;
    ((uint32_t*)(ws + OFF_FDHH8))[(((gt*4 + kt)*64 + lane) << 1) | half] =
        pk4_fp8(W[g*128 + kb], W[g*128 + kb + 1], W[g*128 + kb + 2], W[g*128 + kb + 3]);
    return;
  }
  idx -= 16384;
  if (idx < 16384) {                              // point math -> gt + flat
    float mx = mask_point[idx*2 + 0];
    float my = mask_point[idx*2 + 1];
    float fx = fminf(mx * 0.25f, 127.0f);
    float fy = fminf(my * 0.25f, 127.0f);
    out_gt[idx*2 + 0] = fx * 4.0f;
    out_gt[idx*2 + 1] = fy * 4.0f;
    flat[idx] = (int)(__fmaf_rn(fy, 128.0f, fx)); // fy*128 exact
    return;
  }
}
#define PREP_TOTAL (32*512 + 512 + 512 + 288*64 + 32*64 + 64*64 + 32768 + 16384 + 16384 + 16384)

// ---------------------------------------------------------------------------
// Kernel T: x [16][64][128][128] f32 -> xT [16][128][128][64] f16 (NHWC)
// ---------------------------------------------------------------------------
__global__ __launch_bounds__(256, 2) void transpose_kernel(
    const float* x, uint32_t* xT32) {
  __shared__ float lds[64][257];
  int bid = blockIdx.x;           // 1024 = 16 b x 16 yt x 4 xt
  int xt = bid & 3, yt = (bid >> 2) & 15, b = bid >> 6;
  int x0 = xt * 32, y0 = yt * 8;
  int tx = threadIdx.x & 31, ty = threadIdx.x >> 5;
  #pragma unroll 8
  for (int c = 0; c < 64; ++c)
    lds[c][ty*32 + tx] = x[((b*64 + c)*128 + (y0 + ty))*128 + (x0 + tx)];
  __syncthreads();
  #pragma unroll 8
  for (int r = 0; r < 32; ++r) {
    int i = threadIdx.x + 256*r;    // i = pos*32 + c2
    int c2 = i & 31, pos = i >> 5;
    int yy = pos >> 5, xx = pos & 31;
    float lo = lds[2*c2][yy*32 + xx], hi = lds[2*c2 + 1][yy*32 + xx];
    xT32[((b*128 + y0 + yy)*128 + (x0 + xx))*32 + c2] = packh(lo, hi);
  }
}

// ---------------------------------------------------------------------------
// Kernel 2: fused gathered conv (3x3 -> ReLU -> 1x1) at points, 4 pts/group
// ---------------------------------------------------------------------------
template <int MODE>
__global__ __launch_bounds__(256, 2) void conv_gather_kernel(
    const float* x, const uint32_t* xT32, const int* point_mask,
    const float* conv1_b, const float* conv2_b,
    const char* ws_ro, _Float16* dots_h, const int* flat) {
  __shared__ uint32_t w1s[64*292];    // 74752 B
  __shared__ uint32_t patch2[4*288];  //  4608 B
  __shared__ uint32_t tl2[4*32];      //   512 B

  const uint32_t* w1p = (const uint32_t*)(ws_ro + OFF_W1P);
  const uint32_t* w2p = (const uint32_t*)(ws_ro + OFF_W2P);
  int tid = threadIdx.x;
  for (int i = tid; i < 288*64; i += 256) {
    int i2 = i >> 6, cc = i & 63;
    w1s[cc*292 + i2] = w1p[i];
  }

  int q = tid >> 6, c = tid & 63;
  float c1b = conv1_b[c], c2b = conv2_b[c];

  for (int g = 0; g < 8; ++g) {
    int p0 = blockIdx.x * 32 + g * 4;
    __syncthreads();
    if (MODE == 1) {
      #pragma unroll
      for (int r = 0; r < 5; ++r) {  // 1152 u32 = 4 pts x 288
        int u = tid + 256*r;
        if (u < 1152) {
          int slot = u / 288, w = u - slot*288;
          int tap = w >> 5, c2i = w & 31;
          int p = p0 + slot;
          int fl = flat[p];
          int hh = fl >> 7, ww = fl & 127;
          int b = p >> 10;
          int dy = tap / 3, dx = tap - dy*3;
          int yy = hh + dy - 1, xx = ww + dx - 1;
          uint32_t v = 0u;
          if (yy >= 0 && yy < 128 && xx >= 0 && xx < 128)
            v = xT32[((b*128 + yy)*128 + xx)*32 + c2i];
          patch2[slot*288 + w] = v;
        }
      }
    } else {
      #pragma unroll
      for (int r = 0; r < 9; ++r) {  // 2304 halves = 4 pts x 576
        int l = tid + 256*r;
        int slot = l / 576;
        int within = l - slot*576;
        int cp = within / 9;
        int tap = within - cp*9;
        int p = p0 + slot;
        int fl = flat[p];
        int hh = fl >> 7, ww = fl & 127;
        int b = p >> 10;
        int yy = hh + tap/3 - 1, xx = ww + tap%3 - 1;
        float v = 0.0f;
        if (yy >= 0 && yy < 128 && xx >= 0 && xx < 128)
          v = x[((b*64 + cp)*128 + yy)*128 + xx];
        ((_Float16*)patch2)[l] = (_Float16)v;
      }
    }
    __syncthreads();

    float a0 = c1b, a1 = 0.f, a2 = 0.f, a3 = 0.f;
    int cbase = c * 292, pbase = q * 288;
    #pragma unroll 4
    for (int i2 = 0; i2 < 288; i2 += 4) {
      a0 = fdot2_(w1s[cbase + i2+0], patch2[pbase + i2+0], a0);
      a1 = fdot2_(w1s[cbase + i2+1], patch2[pbase + i2+1], a1);
      a2 = fdot2_(w1s[cbase + i2+2], patch2[pbase + i2+2], a2);
      a3 = fdot2_(w1s[cbase + i2+3], patch2[pbase + i2+3], a3);
    }
    float t1 = fmaxf((a0 + a1) + (a2 + a3), 0.0f);
    ((_Float16*)tl2)[q*64 + c] = (_Float16)t1;
    // tl2[q] written/read by same wave -> no barrier

    float acc2 = c2b;
    #pragma unroll
    for (int c2i = 0; c2i < 32; ++c2i)
      acc2 = fdot2_(w2p[c2i*64 + c], tl2[q*32 + c2i], acc2);
    int p = p0 + q;
    acc2 *= (float)point_mask[p];
    int k = p & 31, bn = p >> 5;
    dots_h[(k*NSEQ + bn)*64 + c] = (_Float16)acc2;   // time-major [k][bn][d]
  }
}

// ---------------------------------------------------------------------------
// Kernel G: encoder x-projection GEMM: gx[R][g] = bias_e[g] + Wih_e . dots[R]
// ---------------------------------------------------------------------------
__global__ __launch_bounds__(512, 4) void gx_gemm_kernel(
    const char* ws_ro, _Float16* gx) {
  const uint32_t* pWih_e = (const uint32_t*)(ws_ro + OFF_PWIH_E);
  const float*    bias_e = (const float*)(ws_ro + OFF_BIAS_E);
  const uint32_t* dots_u = (const uint32_t*)(ws_ro + OFF_DOTS);
  __shared__ uint32_t xs[32][32];   // 4 KB
  int tid = threadIdx.x;
  int R0 = blockIdx.x * 32;
  for (int i = tid; i < 32*32; i += 512)
    xs[i >> 5][i & 31] = dots_u[(R0 + (i >> 5))*32 + (i & 31)];
  uint32_t wv[32];
  #pragma unroll
  for (int k = 0; k < 32; ++k) wv[k] = pWih_e[k*512 + tid];
  float bs = bias_e[tid];
  __syncthreads();
  #pragma unroll 2
  for (int r = 0; r < 32; ++r) {
    float a = bs;
    #pragma unroll
    for (int k = 0; k < 32; ++k) a = fdot2_(wv[k], xs[r][k], a);
    gx[(size_t)(R0 + r)*512 + tid] = (_Float16)a;
  }
}

// ---------------------------------------------------------------------------
// Kernel 3: recurrent LSTMs via MFMA (R5 structure: gb-roundtrip DEDUP
// nonlinearity) + fused MLP head. 256 blocks x 512 threads (8 waves);
// 2 seqs/block. Wave w owns gate-tiles gt = 4w..4w+3.
// Encoder: f16 MFMA (16 frags), x from gx. Decoder: fp8 MFMA (32 frags =
// 64 VGPR, asm-pinned); enc-h and dec-h stored as fp8 bytes in LDS.
// ---------------------------------------------------------------------------
__global__ __launch_bounds__(512, 2) void lstm_head_kernel(
    const char* ws_ro, const _Float16* gx,
    const float* b1, const float* W2, const float* b2,
    float* out_kp) {
  const f16x8* fehh   = (const f16x8*)(ws_ro + OFF_FEHH);
  const uint2* fdih8  = (const uint2*)(ws_ro + OFF_FDIH8);
  const uint2* fdhh8  = (const uint2*)(ws_ro + OFF_FDHH8);
  const float* bias_d = (const float*)(ws_ro + OFF_BIAS_D);
  const uint32_t* W1h = (const uint32_t*)(ws_ro + OFF_W1H);

  __shared__ __attribute__((aligned(16))) uint32_t enc8[2][32][32];   //  8 KB fp8
  __shared__ __attribute__((aligned(16))) uint32_t dech2[2][32][64];  // 16 KB f16
  __shared__ __attribute__((aligned(16))) uint32_t hb2[2][64];        // 512 B f16
  __shared__ __attribute__((aligned(16))) uint32_t hb8[2][32];        // 256 B fp8
  __shared__ __attribute__((aligned(16))) float    gb[2][512];        //  4 KB
  __shared__ float hidf[64][65];                                      // 16.6 KB

  int tid  = threadIdx.x;
  int lane = tid & 63, wave = tid >> 6;
  int col  = lane & 15, lgrp = lane >> 4;
  int bn0  = blockIdx.x * 2;

  int s_nl = tid >> 7, u_nl = tid & 127;    // nonlinearity role (tid < 256)
  float c_reg = 0.0f;

  // encoder h-weights as f16 MFMA fragments (16 frags = 64 VGPRs)
  f16x8 ae[4][4];
  #pragma unroll
  for (int g0 = 0; g0 < 4; ++g0)
    #pragma unroll
    for (int kt = 0; kt < 4; ++kt)
      ae[g0][kt] = fehh[((wave*4 + g0)*4 + kt)*64 + lane];

  if (tid < 128) hb2[tid >> 6][tid & 63] = 0u;
  __syncthreads();

  const f16x8 bzero = {};

  // ----------------- encoder -----------------
  for (int t = 0; t < 32; ++t) {
    // early-issue gx loads (hidden under MFMA phase)
    float gxi = 0.f, gxf = 0.f, gxg = 0.f, gxo = 0.f;
    if (tid < 256) {
      const _Float16* gr = gx + (size_t)(t*512 + bn0 + s_nl)*512;
      gxi = (float)gr[u_nl];       gxf = (float)gr[128 + u_nl];
      gxg = (float)gr[256 + u_nl]; gxo = (float)gr[384 + u_nl];
    }
    f16x8 bf[4];
    #pragma unroll
    for (int kt = 0; kt < 4; ++kt) {
      if (col < 2) bf[kt] = *(const f16x8*)&hb2[col][kt*16 + lgrp*4];
      else         bf[kt] = bzero;
    }
    #pragma unroll
    for (int g0 = 0; g0 < 4; ++g0) {
      f32x4 acc = {0.f, 0.f, 0.f, 0.f};
      #pragma unroll
      for (int kt = 0; kt < 4; ++kt)
        acc = __builtin_amdgcn_mfma_f32_16x16x32_f16(ae[g0][kt], bf[kt], acc, 0, 0, 0);
      if (col < 2)
        *(f32x4*)&gb[col][(wave*4 + g0)*16 + lgrp*4] = acc;
    }
    __syncthreads();
    if (tid < 256) {
      float ig = sig_ (gb[s_nl][u_nl]       + gxi);
      float fg = sig_ (gb[s_nl][128 + u_nl] + gxf);
      float gg = tanh_(gb[s_nl][256 + u_nl] + gxg);
      float og = sig_ (gb[s_nl][384 + u_nl] + gxo);
      c_reg = fg * c_reg + ig * gg;
      float hh = og * tanh_(c_reg);
      ((_Float16*)&hb2[s_nl][0])[u_nl] = (_Float16)hh;  // enc recurrence (f16)
      ((uint8_t*)&enc8[s_nl][t][0])[u_nl] = f8_(hh);    // dec consumption (fp8)
    }
    __syncthreads();
  }

  // ---- transition: dec recurrent h (fp8) = enc final h ----
  if (tid < 256) {
    float hv = (float)((_Float16*)&hb2[s_nl][0])[u_nl];
    ((uint8_t*)&hb8[s_nl][0])[u_nl] = f8_(hv);
  }

  // ---- decoder weights: 32 asm-pinned fp8 frags (64 VGPR) ----
  uint2 dih8[4][4], dhh8[4][4];
  #pragma unroll
  for (int g0 = 0; g0 < 4; ++g0)
    #pragma unroll
    for (int kt = 0; kt < 4; ++kt) {
      dih8[g0][kt] = ldg_frag8(&fdih8[((wave*4 + g0)*4 + kt)*64 + lane]);
      dhh8[g0][kt] = ldg_frag8(&fdhh8[((wave*4 + g0)*4 + kt)*64 + lane]);
    }
  frag_fence();
  float bdi = 0.f, bdf = 0.f, bdg = 0.f, bdo = 0.f;
  if (tid < 256) {
    bdi = bias_d[u_nl];       bdf = bias_d[128 + u_nl];
    bdg = bias_d[256 + u_nl]; bdo = bias_d[384 + u_nl];
  }
  __syncthreads();

  // ----------------- decoder (fp8 MFMA) -----------------
  for (int t = 0; t < 32; ++t) {
    long bx[4], bh[4];
    #pragma unroll
    for (int kt = 0; kt < 4; ++kt) {
      if (col < 2) {
        bx[kt] = u2l(*(const uint2*)&enc8[col][t][kt*8 + lgrp*2]);
        bh[kt] = u2l(*(const uint2*)&hb8[col][kt*8 + lgrp*2]);
      } else { bx[kt] = 0; bh[kt] = 0; }
    }
    #pragma unroll
    for (int g0 = 0; g0 < 4; ++g0) {
      f32x4 acc = {0.f, 0.f, 0.f, 0.f};
      #pragma unroll
      for (int kt = 0; kt < 4; ++kt)
        acc = __builtin_amdgcn_mfma_f32_16x16x32_fp8_fp8(
            u2l(dih8[g0][kt]), bx[kt], acc, 0, 0, 0);
      #pragma unroll
      for (int kt = 0; kt < 4; ++kt)
        acc = __builtin_amdgcn_mfma_f32_16x16x32_fp8_fp8(
            u2l(dhh8[g0][kt]), bh[kt], acc, 0, 0, 0);
      if (col < 2)
        *(f32x4*)&gb[col][(wave*4 + g0)*16 + lgrp*4] = acc;
    }
    __syncthreads();
    if (tid < 256) {
      float ig = sig_ (gb[s_nl][u_nl]       + bdi);
      float fg = sig_ (gb[s_nl][128 + u_nl] + bdf);
      float gg = tanh_(gb[s_nl][256 + u_nl] + bdg);
      float og = sig_ (gb[s_nl][384 + u_nl] + bdo);
      c_reg = fg * c_reg + ig * gg;
      float hh = og * tanh_(c_reg);
      ((uint8_t*)&hb8[s_nl][0])[u_nl] = f8_(hh);            // dec recurrence
      ((_Float16*)&dech2[s_nl][t][0])[u_nl] = (_Float16)hh; // head input (f16)
    }
    __syncthreads();
  }

  // ----------------- fused head: relu(dec@W1.T+b1)@W2.T+b2 ----------------
  {
    int j = tid & 63, w = tid >> 6;       // 8 waves; rows st = w + 8*m
    float acc[8];
    #pragma unroll
    for (int m = 0; m < 8; ++m) acc[m] = b1[j];
    #pragma unroll 8
    for (int k = 0; k < 64; ++k) {
      uint32_t wv = W1h[k*64 + j];
      #pragma unroll
      for (int m = 0; m < 8; ++m) {
        int st = w + 8*m;
        acc[m] = fdot2_(wv, dech2[st >> 5][st & 31][k], acc[m]);
      }
    }
    #pragma unroll
    for (int m = 0; m < 8; ++m) {
      int st = w + 8*m;
      hidf[st][j] = fmaxf(acc[m], 0.0f);
    }
  }
  __syncthreads();
  if (tid < 128) {
    int st = tid >> 1, e = tid & 1;
    float acc = b2[e];
    #pragma unroll 16
    for (int j = 0; j < 64; ++j) acc += W2[e*64 + j] * hidf[st][j];
    int s = st >> 5, t = st & 31;
    out_kp[((bn0 + s)*32 + t)*2 + e] = acc;
  }
}

// ---------------------------------------------------------------------------
// Launch
// ---------------------------------------------------------------------------
extern "C" void kernel_launch(void* const* d_in, const int* in_sizes, int n_in,
                              void* d_out, int out_size, void* d_ws, size_t ws_size,
                              hipStream_t stream) {
  const float* x          = (const float*)d_in[0];
  const float* mask_point = (const float*)d_in[1];
  const int*   point_mask = (const int*)d_in[2];
  const float* conv1_w    = (const float*)d_in[3];
  const float* conv1_b    = (const float*)d_in[4];
  const float* conv2_w    = (const float*)d_in[5];
  const float* conv2_b    = (const float*)d_in[6];
  const float* Wih_e      = (const float*)d_in[7];
  const float* Whh_e      = (const float*)d_in[8];
  const float* bih_e      = (const float*)d_in[9];
  const float* bhh_e      = (const float*)d_in[10];
  const float* Wih_d      = (const float*)d_in[11];
  const float* Whh_d      = (const float*)d_in[12];
  const float* bih_d      = (const float*)d_in[13];
  const float* bhh_d      = (const float*)d_in[14];
  const float* W1         = (const float*)d_in[15];
  const float* b1         = (const float*)d_in[16];
  const float* W2         = (const float*)d_in[17];
  const float* b2         = (const float*)d_in[18];

  float* out = (float*)d_out;
  char*  ws  = (char*)d_ws;

  const bool use_xt = (ws_size >= WS_NEED_XT);
  // gx overlays the xT region (dead after conv_gather); fallback otherwise
  _Float16* gx = (_Float16*)(ws + (use_xt ? OFF_XT : OFF_GX_FB));

  prep_kernel<<<(PREP_TOTAL + 255)/256, 256, 0, stream>>>(
      Wih_e, Whh_e, bih_e, bhh_e, Wih_d, Whh_d, bih_d, bhh_d,
      conv1_w, conv2_w, W1, mask_point, out + 32768, (int*)(ws + OFF_FLAT),
      ws, use_xt ? 1 : 0);

  if (use_xt) {
    transpose_kernel<<<1024, 256, 0, stream>>>(x, (uint32_t*)(ws + OFF_XT));
    conv_gather_kernel<1><<<512, 256, 0, stream>>>(
        x, (const uint32_t*)(ws + OFF_XT), point_mask, conv1_b, conv2_b,
        ws, (_Float16*)(ws + OFF_DOTS), (const int*)(ws + OFF_FLAT));
  } else {
    conv_gather_kernel<0><<<512, 256, 0, stream>>>(
        x, nullptr, point_mask, conv1_b, conv2_b,
        ws, (_Float16*)(ws + OFF_DOTS), (const int*)(ws + OFF_FLAT));
  }

  gx_gemm_kernel<<<512, 512, 0, stream>>>(ws, gx);

  lstm_head_kernel<<<256, 512, 0, stream>>>(ws, gx, b1, W2, b2, out);
}